// Round 3
// baseline (613.833 us; speedup 1.0000x reference)
//
#include <hip/hip_runtime.h>
#include <hip/hip_bf16.h>
#include <cstdint>
#include <cstddef>

typedef unsigned short u16;
typedef __bf16 bf16x8 __attribute__((ext_vector_type(8)));
typedef float f32x4 __attribute__((ext_vector_type(4)));

#define EPSF 1e-5f

__device__ __forceinline__ float b2f(u16 u) {
  unsigned int i = ((unsigned int)u) << 16;
  return __builtin_bit_cast(float, i);
}
__device__ __forceinline__ u16 f2b(float f) {
  unsigned int u = __builtin_bit_cast(unsigned int, f);
  u = u + 0x7fffu + ((u >> 16) & 1u);  // round-to-nearest-even
  return (u16)(u >> 16);
}

// ---------------- kernel 0: input dtype detection --------------------------
// fp32 storage read as u16: low-mantissa words have uniform-random exponent
// bits -> |v|>1e4 or NaN guaranteed among 2048 such words. bf16 N(0,1): |x|<6.
__global__ __launch_bounds__(256) void detect_kernel(const u16* __restrict__ Xu,
                                                     int* __restrict__ flag) {
  int bad = 0;
  for (int i = threadIdx.x; i < 4096; i += 256) {
    float a = fabsf(b2f(Xu[i]));
    if (!(a <= 1e4f)) bad = 1;  // catches huge AND NaN
  }
  if (bad) atomicOr(flag, 1);
}

// ---------------- kernel 1: A -> bf16 (Abf), dual dtype --------------------
__global__ __launch_bounds__(256) void convertA_kernel(const void* __restrict__ A,
                                                       u16* __restrict__ Abf,
                                                       const int* __restrict__ flag) {
  const int isf32 = *flag;
  const size_t i = (size_t)blockIdx.x * 256 + threadIdx.x;  // 8 elems each
  if (isf32) {
    const float4* Af = (const float4*)A;
    float4 a = Af[i * 2], b = Af[i * 2 + 1];
    u16 o[8] = {f2b(a.x), f2b(a.y), f2b(a.z), f2b(a.w),
                f2b(b.x), f2b(b.y), f2b(b.z), f2b(b.w)};
    *(uint4*)(Abf + i * 8) = *(const uint4*)o;
  } else {
    *(uint4*)(Abf + i * 8) = ((const uint4*)A)[i];
  }
}

// ---------------- kernel 2: build F^T [12288][2048] bf16 -------------------
__global__ __launch_bounds__(256) void build_f_kernel(const void* __restrict__ X,
                                                      u16* __restrict__ Ft,
                                                      const int* __restrict__ flag) {
  const int isf32 = *flag;
  const int blk = blockIdx.x;        // (bp*32 + ch)*8 + mc
  const int mc = blk & 7;
  const int chbp = blk >> 3;
  const int ch = chbp & 31;
  const int bp = chbp >> 5;
  const int b = bp / 12, p = bp % 12;
  const int m = mc * 256 + threadIdx.x;
  const size_t xi = ((size_t)(b * 32 + ch) * 2048 + m) * 12 + p;
  const float x = isf32 ? ((const float*)X)[xi] : b2f(((const u16*)X)[xi]);
  const float x2 = x * x, x3 = x2 * x, x4 = x2 * x2;
  const float e = __expf(x), en = __expf(-x);
  const float vals[8] = {x, x2, x3, x4, x * e, e, x * en, en};
  const size_t cb = (size_t)bp * 256 + ch;
#pragma unroll
  for (int f = 0; f < 8; ++f)
    Ft[(cb + (size_t)f * 32) * 2048 + m] = f2b(vals[f]);
}

// ---------------- kernel 3: degree / log-degree / sum(logd) ----------------
__global__ __launch_bounds__(256) void deg_kernel(const u16* __restrict__ Abf,
                                                  float* __restrict__ deg,
                                                  float* __restrict__ logd,
                                                  float* __restrict__ dsum) {
  const int i = blockIdx.x;
  const int tid = threadIdx.x;
  const u16* row = Abf + (size_t)i * 2048;
  float s = 0.f;
  for (int j = tid; j < 2048; j += 256) s += b2f(row[j]);
#pragma unroll
  for (int off = 32; off > 0; off >>= 1) s += __shfl_down(s, off, 64);
  __shared__ float red[4];
  const int lane = tid & 63, w = tid >> 6;
  if (lane == 0) red[w] = s;
  __syncthreads();
  if (tid == 0) {
    float t = red[0] + red[1] + red[2] + red[3];
    deg[i] = t;
    float ld = logf(t + 1.f);
    logd[i] = ld;
    atomicAdd(dsum, ld);
  }
}

// ---------------- kernel 4: Theta transpose -> ThT [32][672] ---------------
__global__ __launch_bounds__(256) void thetaT_kernel(const void* __restrict__ Th,
                                                     u16* __restrict__ ThT,
                                                     const int* __restrict__ flag) {
  const int isf32 = *flag;
  const int e = blockIdx.x * 256 + threadIdx.x;
  if (e < 21504) {
    const int k = e >> 5, o = e & 31;
    ThT[o * 672 + k] = isf32 ? f2b(((const float*)Th)[e]) : ((const u16*)Th)[e];
  }
}

// ---------------- kernel 5: GEMM Y = Abf @ F (classic LDS staging) ---------
// M=2048 (i), N=12288 (col), K=2048 (m). Abf row-major [M][K], Ft = B^T [N][K].
__global__ __launch_bounds__(256) void gemm_kernel(const u16* __restrict__ A,
                                                   const u16* __restrict__ Ft,
                                                   u16* __restrict__ Y) {
  __shared__ __attribute__((aligned(16))) u16 As[128 * 64];  // [row][k]
  __shared__ __attribute__((aligned(16))) u16 Bs[128 * 64];  // [col][k]
  const int tid = threadIdx.x;
  const int wave = tid >> 6;
  const int lane = tid & 63;
  const int l15 = lane & 15;
  const int quad = lane >> 4;
  const int wm = wave >> 1;
  const int wn = wave & 1;
  const int bn = blockIdx.x;   // 0..95
  const int bm = blockIdx.y;   // 0..15

  const int srow = tid >> 3;          // 0..31
  const int scol = (tid & 7) << 3;    // 0,8,..,56
  const u16* gA = A  + (size_t)(bm * 128 + srow) * 2048 + scol;
  const u16* gB = Ft + (size_t)(bn * 128 + srow) * 2048 + scol;

  f32x4 acc[4][4];
#pragma unroll
  for (int i = 0; i < 4; ++i)
#pragma unroll
    for (int j = 0; j < 4; ++j) acc[i][j] = (f32x4){0.f, 0.f, 0.f, 0.f};

  for (int kk = 0; kk < 2048; kk += 64) {
    uint4 ra[4], rb[4];
#pragma unroll
    for (int r = 0; r < 4; ++r) {
      ra[r] = *(const uint4*)(gA + (size_t)r * 32 * 2048 + kk);
      rb[r] = *(const uint4*)(gB + (size_t)r * 32 * 2048 + kk);
    }
    __syncthreads();  // previous iter's LDS reads done before overwrite
#pragma unroll
    for (int r = 0; r < 4; ++r) {
      *(uint4*)(As + (r * 32 + srow) * 64 + scol) = ra[r];  // per-wave: 1KB contig
      *(uint4*)(Bs + (r * 32 + srow) * 64 + scol) = rb[r];
    }
    __syncthreads();
#pragma unroll
    for (int ks = 0; ks < 2; ++ks) {
      bf16x8 af[4], bfr[4];
#pragma unroll
      for (int t = 0; t < 4; ++t)
        af[t] = *(const bf16x8*)(As + (wm * 64 + t * 16 + l15) * 64 + ks * 32 + quad * 8);
#pragma unroll
      for (int t = 0; t < 4; ++t)
        bfr[t] = *(const bf16x8*)(Bs + (wn * 64 + t * 16 + l15) * 64 + ks * 32 + quad * 8);
#pragma unroll
      for (int mt = 0; mt < 4; ++mt)
#pragma unroll
        for (int nt = 0; nt < 4; ++nt)
          acc[mt][nt] = __builtin_amdgcn_mfma_f32_16x16x32_bf16(af[mt], bfr[nt],
                                                                acc[mt][nt], 0, 0, 0);
    }
  }

#pragma unroll
  for (int mt = 0; mt < 4; ++mt)
#pragma unroll
    for (int nt = 0; nt < 4; ++nt) {
      const int row = bm * 128 + wm * 64 + mt * 16 + quad * 4;
      const int col = bn * 128 + wn * 64 + nt * 16 + l15;
#pragma unroll
      for (int j = 0; j < 4; ++j)
        Y[(size_t)(row + j) * 12288 + col] = f2b(acc[mt][nt][j]);
    }
}

// ---------------- kernel 6: epilogue (features + MFMA projection) ----------
__global__ __launch_bounds__(256) void epilogue_kernel(
    const u16* __restrict__ Y, const void* __restrict__ X,
    const float* __restrict__ deg, const float* __restrict__ logd,
    const float* __restrict__ dsum, const u16* __restrict__ ThT,
    const void* __restrict__ Bias, void* __restrict__ out,
    const int* __restrict__ flag) {
  __shared__ __attribute__((aligned(16))) u16 feats[32 * 680];
  const int isf32 = *flag;
  const int tid = threadIdx.x;
  const int nc = blockIdx.x;   // 0..63 node chunk
  const int bp = blockIdx.y;   // 0..47
  const int b = bp / 12, p = bp % 12;
  const float delta = dsum[0] * (1.0f / 2048.0f);

  const int nl = tid >> 3;     // 0..31 local node
  const int chg = tid & 7;     // 4 channels each
  const int i = nc * 32 + nl;
  const float d = fmaxf(deg[i], EPSF);
  const float s = logd[i] / delta;
  const float is = 1.0f / fmaxf(s, EPSF);
  const u16* yrow = Y + (size_t)i * 12288 + (size_t)bp * 256;
#pragma unroll
  for (int cc = 0; cc < 4; ++cc) {
    const int ch = chg * 4 + cc;
    const float m1 = b2f(yrow[ch]) / d;
    const float m2 = b2f(yrow[32 + ch]) / d;
    const float m3 = b2f(yrow[64 + ch]) / d;
    const float m4 = b2f(yrow[96 + ch]) / d;
    const float smx = b2f(yrow[128 + ch]) / (b2f(yrow[160 + ch]) + EPSF);
    const float smn = b2f(yrow[192 + ch]) / (b2f(yrow[224 + ch]) + EPSF);
    const size_t xi = ((size_t)(b * 32 + ch) * 2048 + i) * 12 + p;
    const float x = isf32 ? ((const float*)X)[xi] : b2f(((const u16*)X)[xi]);
    const float var = fmaxf(m2 - m1 * m1, 0.f);
    const float stdv = sqrtf(var + EPSF);
    const float x2 = x * x, x3 = x2 * x, x4 = x2 * x2;
    const float dist = x2 - 2.f * x * m1 + m2;
    const float ed2 = x4 - 4.f * x3 * m1 + 6.f * x2 * m2 - 4.f * x * m3 + m4;
    const float dstd = sqrtf(fmaxf(ed2 - dist * dist, 0.f) + EPSF);
    const float f7[7] = {smn, smx, m1, stdv, var, dist, dstd};
#pragma unroll
    for (int a = 0; a < 7; ++a) {
      const int k = a * 32 + ch;
      feats[nl * 680 + k]       = f2b(f7[a]);
      feats[nl * 680 + 224 + k] = f2b(f7[a] * s);
      feats[nl * 680 + 448 + k] = f2b(f7[a] * is);
    }
  }
  __syncthreads();

  const int wave = tid >> 6, lane = tid & 63;
  const int l15 = lane & 15, quad = lane >> 4;
  const int mt = wave >> 1, nt = wave & 1;  // 2x2 of 16x16
  f32x4 acc = (f32x4){0.f, 0.f, 0.f, 0.f};
#pragma unroll
  for (int kt = 0; kt < 21; ++kt) {  // K = 672
    bf16x8 a  = *(const bf16x8*)(feats + (mt * 16 + l15) * 680 + kt * 32 + quad * 8);
    bf16x8 bb = *(const bf16x8*)(ThT + (size_t)(nt * 16 + l15) * 672 + kt * 32 + quad * 8);
    acc = __builtin_amdgcn_mfma_f32_16x16x32_bf16(a, bb, acc, 0, 0, 0);
  }
#pragma unroll
  for (int j = 0; j < 4; ++j) {
    const int node = mt * 16 + quad * 4 + j;
    const int o = nt * 16 + l15;
    const float bias = isf32 ? ((const float*)Bias)[o] : b2f(((const u16*)Bias)[o]);
    float v = acc[j] + bias;
    v = v > 0.f ? v : 0.01f * v;   // leaky_relu
    const int ig = nc * 32 + node;
    const size_t oi = ((size_t)(b * 32 + o) * 2048 + ig) * 12 + p;
    if (isf32) ((float*)out)[oi] = v;       // fp32 dataset -> fp32 output
    else       ((u16*)out)[oi]   = f2b(v);  // bf16 dataset -> bf16 output
  }
}

// ---------------------------------------------------------------------------
extern "C" void kernel_launch(void* const* d_in, const int* in_sizes, int n_in,
                              void* d_out, int out_size, void* d_ws, size_t ws_size,
                              hipStream_t stream) {
  const void* X    = d_in[0];
  const void* A    = d_in[1];
  const void* Th   = d_in[2];
  const void* Bias = d_in[3];
  char* ws = (char*)d_ws;

  // workspace layout (bytes): ~109 MB total
  u16*   Ft   = (u16*)(ws);                       // 12288*2048*2 = 50331648
  u16*   Y    = (u16*)(ws + 50331648);            // 2048*12288*2 = 50331648
  u16*   Abf  = (u16*)(ws + 100663296);           // 2048*2048*2  = 8388608
  float* deg  = (float*)(ws + 109051904);         // 8192
  float* logd = (float*)(ws + 109060096);         // 8192
  u16*   ThT  = (u16*)(ws + 109068288);           // 43008
  float* dsum = (float*)(ws + 109111296);         // 4
  int*   flag = (int*)(ws + 109111300);           // 4

  hipMemsetAsync(dsum, 0, 8, stream);  // zeroes dsum + flag
  detect_kernel<<<1, 256, 0, stream>>>((const u16*)X, flag);
  convertA_kernel<<<2048, 256, 0, stream>>>(A, Abf, flag);
  build_f_kernel<<<12288, 256, 0, stream>>>(X, Ft, flag);
  deg_kernel<<<2048, 256, 0, stream>>>(Abf, deg, logd, dsum);
  thetaT_kernel<<<84, 256, 0, stream>>>(Th, ThT, flag);
  gemm_kernel<<<dim3(96, 16), 256, 0, stream>>>(Abf, Ft, Y);
  epilogue_kernel<<<dim3(64, 48), 256, 0, stream>>>(Y, X, deg, logd, dsum, ThT, Bias, d_out, flag);
}

// Round 4
// 308.171 us; speedup vs baseline: 1.9919x; 1.9919x over previous
//
#include <hip/hip_runtime.h>
#include <hip/hip_bf16.h>
#include <cstdint>
#include <cstddef>

typedef unsigned short u16;
typedef __bf16 bf16x8 __attribute__((ext_vector_type(8)));
typedef float f32x4 __attribute__((ext_vector_type(4)));

#define EPSF 1e-5f

__device__ __forceinline__ float b2f(u16 u) {
  unsigned int i = ((unsigned int)u) << 16;
  return __builtin_bit_cast(float, i);
}
__device__ __forceinline__ u16 f2b(float f) {
  unsigned int u = __builtin_bit_cast(unsigned int, f);
  u = u + 0x7fffu + ((u >> 16) & 1u);  // round-to-nearest-even
  return (u16)(u >> 16);
}

// async global->LDS, 16B/lane. HW dest = wave-uniform base + lane*16; we pass
// per-lane base+lane*16 (robust under both semantics: lane0's value == base).
__device__ __forceinline__ void async_load16(const u16* g, u16* l) {
  __builtin_amdgcn_global_load_lds(
      (__attribute__((address_space(1))) void*)(g),
      (__attribute__((address_space(3))) void*)(l), 16, 0, 0);
}

// ---------------- kernel 0: input dtype detection --------------------------
__global__ __launch_bounds__(256) void detect_kernel(const u16* __restrict__ Xu,
                                                     int* __restrict__ flag) {
  int bad = 0;
  for (int i = threadIdx.x; i < 4096; i += 256) {
    float a = fabsf(b2f(Xu[i]));
    if (!(a <= 1e4f)) bad = 1;  // catches huge AND NaN
  }
  if (bad) atomicOr(flag, 1);
}

// ---------------- kernel 1: A -> bf16 (Abf), dual dtype --------------------
__global__ __launch_bounds__(256) void convertA_kernel(const void* __restrict__ A,
                                                       u16* __restrict__ Abf,
                                                       const int* __restrict__ flag) {
  const int isf32 = *flag;
  const size_t i = (size_t)blockIdx.x * 256 + threadIdx.x;  // 8 elems each
  if (isf32) {
    const float4* Af = (const float4*)A;
    float4 a = Af[i * 2], b = Af[i * 2 + 1];
    u16 o[8] = {f2b(a.x), f2b(a.y), f2b(a.z), f2b(a.w),
                f2b(b.x), f2b(b.y), f2b(b.z), f2b(b.w)};
    *(uint4*)(Abf + i * 8) = *(const uint4*)o;
  } else {
    *(uint4*)(Abf + i * 8) = ((const uint4*)A)[i];
  }
}

// ---------------- kernel 2: build F^T [12288][2048] bf16 -------------------
__global__ __launch_bounds__(256) void build_f_kernel(const void* __restrict__ X,
                                                      u16* __restrict__ Ft,
                                                      const int* __restrict__ flag) {
  const int isf32 = *flag;
  const int blk = blockIdx.x;        // (bp*32 + ch)*8 + mc
  const int mc = blk & 7;
  const int chbp = blk >> 3;
  const int ch = chbp & 31;
  const int bp = chbp >> 5;
  const int b = bp / 12, p = bp % 12;
  const int m = mc * 256 + threadIdx.x;
  const size_t xi = ((size_t)(b * 32 + ch) * 2048 + m) * 12 + p;
  const float x = isf32 ? ((const float*)X)[xi] : b2f(((const u16*)X)[xi]);
  const float x2 = x * x, x3 = x2 * x, x4 = x2 * x2;
  const float e = __expf(x), en = __expf(-x);
  const float vals[8] = {x, x2, x3, x4, x * e, e, x * en, en};
  const size_t cb = (size_t)bp * 256 + ch;
#pragma unroll
  for (int f = 0; f < 8; ++f)
    Ft[(cb + (size_t)f * 32) * 2048 + m] = f2b(vals[f]);
}

// ---------------- kernel 3: degree / log-degree / sum(logd) ----------------
__global__ __launch_bounds__(256) void deg_kernel(const u16* __restrict__ Abf,
                                                  float* __restrict__ deg,
                                                  float* __restrict__ logd,
                                                  float* __restrict__ dsum) {
  const int i = blockIdx.x;
  const int tid = threadIdx.x;
  const u16* row = Abf + (size_t)i * 2048;
  float s = 0.f;
  for (int j = tid; j < 2048; j += 256) s += b2f(row[j]);
#pragma unroll
  for (int off = 32; off > 0; off >>= 1) s += __shfl_down(s, off, 64);
  __shared__ float red[4];
  const int lane = tid & 63, w = tid >> 6;
  if (lane == 0) red[w] = s;
  __syncthreads();
  if (tid == 0) {
    float t = red[0] + red[1] + red[2] + red[3];
    deg[i] = t;
    float ld = logf(t + 1.f);
    logd[i] = ld;
    atomicAdd(dsum, ld);
  }
}

// ---------------- kernel 4: Theta transpose -> ThT [32][672] ---------------
__global__ __launch_bounds__(256) void thetaT_kernel(const void* __restrict__ Th,
                                                     u16* __restrict__ ThT,
                                                     const int* __restrict__ flag) {
  const int isf32 = *flag;
  const int e = blockIdx.x * 256 + threadIdx.x;
  if (e < 21504) {
    const int k = e >> 5, o = e & 31;
    ThT[o * 672 + k] = isf32 ? f2b(((const float*)Th)[e]) : ((const u16*)Th)[e];
  }
}

// ---------------- kernel 5: GEMM Y = Abf @ F (m97 async + swizzle) ---------
// M=2048 (i), N=12288 (col), K=2048 (m). Abf row-major [M][K], Ft = B^T [N][K].
// LDS layout chunk-swizzled: LDS[row][c8] = global[row][c8 ^ (row&7)] (16B
// chunks) -> conflict-free ds_read_b128 fragments. C staged via LDS for
// full-line coalesced Y writes (fixes 25x write amplification of r2).
__global__ __launch_bounds__(256) void gemm_kernel(const u16* __restrict__ A,
                                                   const u16* __restrict__ Ft,
                                                   u16* __restrict__ Y) {
  __shared__ __attribute__((aligned(16))) u16 smem[2 * 128 * 64];  // 32 KB
  u16* As = smem;             // [128][64]
  u16* Bs = smem + 128 * 64;  // [128][64]
  const int tid = threadIdx.x;
  const int wave = tid >> 6;
  const int lane = tid & 63;
  const int l15 = lane & 15;
  const int quad = lane >> 4;
  const int wm = wave >> 1;
  const int wn = wave & 1;

  // XCD-aware remap: XCD k (= blockIdx%8 heuristic) owns bm in {2k, 2k+1} ->
  // its 128 A-rows (0.5 MB) stay hot in that XCD's L2 across 96 bn-blocks.
  const int f = blockIdx.x;          // 0..1535
  const int xcd = f & 7;
  const int jj = f >> 3;             // 0..191
  const int bm = xcd * 2 + (jj >= 96 ? 1 : 0);
  const int bn = jj % 96;

  const int lrow = lane >> 3;                    // 0..7
  const int schunk = (lane & 7) ^ lrow;          // swizzled source chunk
  const u16* gA = A  + (size_t)(bm * 128 + wave * 32 + lrow) * 2048 + schunk * 8;
  const u16* gB = Ft + (size_t)(bn * 128 + wave * 32 + lrow) * 2048 + schunk * 8;
  u16* lA = As + wave * 32 * 64 + lane * 8;  // per-lane dest (base + lane*16B)
  u16* lB = Bs + wave * 32 * 64 + lane * 8;

  f32x4 acc[4][4];
#pragma unroll
  for (int i = 0; i < 4; ++i)
#pragma unroll
    for (int j = 0; j < 4; ++j) acc[i][j] = (f32x4){0.f, 0.f, 0.f, 0.f};

  for (int kk = 0; kk < 2048; kk += 64) {
    __syncthreads();  // prev iter's LDS reads done before overwrite
#pragma unroll
    for (int i = 0; i < 4; ++i) {
      async_load16(gA + (size_t)i * (8 * 2048) + kk, lA + i * (8 * 64));
      async_load16(gB + (size_t)i * (8 * 2048) + kk, lB + i * (8 * 64));
    }
    __syncthreads();  // compiler drains vmcnt(0) before s_barrier
#pragma unroll
    for (int ks = 0; ks < 2; ++ks) {
      const int ca = ((ks * 4 + quad) ^ (l15 & 7)) * 8;  // un-swizzle chunk
      bf16x8 af[4], bfr[4];
#pragma unroll
      for (int t = 0; t < 4; ++t)
        af[t] = *(const bf16x8*)(As + (wm * 64 + t * 16 + l15) * 64 + ca);
#pragma unroll
      for (int t = 0; t < 4; ++t)
        bfr[t] = *(const bf16x8*)(Bs + (wn * 64 + t * 16 + l15) * 64 + ca);
#pragma unroll
      for (int mt = 0; mt < 4; ++mt)
#pragma unroll
        for (int nt = 0; nt < 4; ++nt)
          acc[mt][nt] = __builtin_amdgcn_mfma_f32_16x16x32_bf16(af[mt], bfr[nt],
                                                                acc[mt][nt], 0, 0, 0);
    }
  }

  // ---- C epilogue: stage bf16 C-tile in LDS (aliases As/Bs), write 16B/lane
  __syncthreads();  // all K-loop LDS reads complete before aliasing
  u16* Cs = smem;   // [128][128] u16 = 32 KB
#pragma unroll
  for (int mt = 0; mt < 4; ++mt)
#pragma unroll
    for (int nt = 0; nt < 4; ++nt) {
      const int row = wm * 64 + mt * 16 + quad * 4;
      const int col = wn * 64 + nt * 16 + l15;
#pragma unroll
      for (int j = 0; j < 4; ++j)
        Cs[(row + j) * 128 + col] = f2b(acc[mt][nt][j]);
    }
  __syncthreads();
  const size_t ybase = (size_t)(bm * 128) * 12288 + (size_t)bn * 128;
#pragma unroll
  for (int q = 0; q < 8; ++q) {
    const int id = q * 256 + tid;           // 0..2047
    const int r = id >> 4, c = (id & 15) * 8;
    *(uint4*)(Y + ybase + (size_t)r * 12288 + c) = *(const uint4*)(Cs + r * 128 + c);
  }
}

// ---------------- kernel 6: epilogue (features + MFMA projection) ----------
__global__ __launch_bounds__(256) void epilogue_kernel(
    const u16* __restrict__ Y, const void* __restrict__ X,
    const float* __restrict__ deg, const float* __restrict__ logd,
    const float* __restrict__ dsum, const u16* __restrict__ ThT,
    const void* __restrict__ Bias, void* __restrict__ out,
    const int* __restrict__ flag) {
  __shared__ __attribute__((aligned(16))) u16 feats[32 * 680];
  const int isf32 = *flag;
  const int tid = threadIdx.x;
  const int nc = blockIdx.x;   // 0..63 node chunk
  const int bp = blockIdx.y;   // 0..47
  const int b = bp / 12, p = bp % 12;
  const float delta = dsum[0] * (1.0f / 2048.0f);

  const int nl = tid >> 3;     // 0..31 local node
  const int chg = tid & 7;     // 4 channels each
  const int i = nc * 32 + nl;
  const float d = fmaxf(deg[i], EPSF);
  const float s = logd[i] / delta;
  const float is = 1.0f / fmaxf(s, EPSF);
  const u16* yrow = Y + (size_t)i * 12288 + (size_t)bp * 256;
#pragma unroll
  for (int cc = 0; cc < 4; ++cc) {
    const int ch = chg * 4 + cc;
    const float m1 = b2f(yrow[ch]) / d;
    const float m2 = b2f(yrow[32 + ch]) / d;
    const float m3 = b2f(yrow[64 + ch]) / d;
    const float m4 = b2f(yrow[96 + ch]) / d;
    const float smx = b2f(yrow[128 + ch]) / (b2f(yrow[160 + ch]) + EPSF);
    const float smn = b2f(yrow[192 + ch]) / (b2f(yrow[224 + ch]) + EPSF);
    const size_t xi = ((size_t)(b * 32 + ch) * 2048 + i) * 12 + p;
    const float x = isf32 ? ((const float*)X)[xi] : b2f(((const u16*)X)[xi]);
    const float var = fmaxf(m2 - m1 * m1, 0.f);
    const float stdv = sqrtf(var + EPSF);
    const float x2 = x * x, x3 = x2 * x, x4 = x2 * x2;
    const float dist = x2 - 2.f * x * m1 + m2;
    const float ed2 = x4 - 4.f * x3 * m1 + 6.f * x2 * m2 - 4.f * x * m3 + m4;
    const float dstd = sqrtf(fmaxf(ed2 - dist * dist, 0.f) + EPSF);
    const float f7[7] = {smn, smx, m1, stdv, var, dist, dstd};
#pragma unroll
    for (int a = 0; a < 7; ++a) {
      const int k = a * 32 + ch;
      feats[nl * 680 + k]       = f2b(f7[a]);
      feats[nl * 680 + 224 + k] = f2b(f7[a] * s);
      feats[nl * 680 + 448 + k] = f2b(f7[a] * is);
    }
  }
  __syncthreads();

  const int wave = tid >> 6, lane = tid & 63;
  const int l15 = lane & 15, quad = lane >> 4;
  const int mt = wave >> 1, nt = wave & 1;  // 2x2 of 16x16
  f32x4 acc = (f32x4){0.f, 0.f, 0.f, 0.f};
#pragma unroll
  for (int kt = 0; kt < 21; ++kt) {  // K = 672
    bf16x8 a  = *(const bf16x8*)(feats + (mt * 16 + l15) * 680 + kt * 32 + quad * 8);
    bf16x8 bb = *(const bf16x8*)(ThT + (size_t)(nt * 16 + l15) * 672 + kt * 32 + quad * 8);
    acc = __builtin_amdgcn_mfma_f32_16x16x32_bf16(a, bb, acc, 0, 0, 0);
  }
#pragma unroll
  for (int j = 0; j < 4; ++j) {
    const int node = mt * 16 + quad * 4 + j;
    const int o = nt * 16 + l15;
    const float bias = isf32 ? ((const float*)Bias)[o] : b2f(((const u16*)Bias)[o]);
    float v = acc[j] + bias;
    v = v > 0.f ? v : 0.01f * v;   // leaky_relu
    const int ig = nc * 32 + node;
    const size_t oi = ((size_t)(b * 32 + o) * 2048 + ig) * 12 + p;
    if (isf32) ((float*)out)[oi] = v;       // fp32 dataset -> fp32 output
    else       ((u16*)out)[oi]   = f2b(v);  // bf16 dataset -> bf16 output
  }
}

// ---------------------------------------------------------------------------
extern "C" void kernel_launch(void* const* d_in, const int* in_sizes, int n_in,
                              void* d_out, int out_size, void* d_ws, size_t ws_size,
                              hipStream_t stream) {
  const void* X    = d_in[0];
  const void* A    = d_in[1];
  const void* Th   = d_in[2];
  const void* Bias = d_in[3];
  char* ws = (char*)d_ws;

  // workspace layout (bytes): ~109 MB total
  u16*   Ft   = (u16*)(ws);                       // 12288*2048*2 = 50331648
  u16*   Y    = (u16*)(ws + 50331648);            // 2048*12288*2 = 50331648
  u16*   Abf  = (u16*)(ws + 100663296);           // 2048*2048*2  = 8388608
  float* deg  = (float*)(ws + 109051904);         // 8192
  float* logd = (float*)(ws + 109060096);         // 8192
  u16*   ThT  = (u16*)(ws + 109068288);           // 43008
  float* dsum = (float*)(ws + 109111296);         // 4
  int*   flag = (int*)(ws + 109111300);           // 4

  hipMemsetAsync(dsum, 0, 8, stream);  // zeroes dsum + flag
  detect_kernel<<<1, 256, 0, stream>>>((const u16*)X, flag);
  convertA_kernel<<<2048, 256, 0, stream>>>(A, Abf, flag);
  build_f_kernel<<<12288, 256, 0, stream>>>(X, Ft, flag);
  deg_kernel<<<2048, 256, 0, stream>>>(Abf, deg, logd, dsum);
  thetaT_kernel<<<84, 256, 0, stream>>>(Th, ThT, flag);
  gemm_kernel<<<1536, 256, 0, stream>>>(Abf, Ft, Y);
  epilogue_kernel<<<dim3(64, 48), 256, 0, stream>>>(Y, X, deg, logd, dsum, ThT, Bias, d_out, flag);
}

// Round 5
// 283.714 us; speedup vs baseline: 2.1636x; 1.0862x over previous
//
#include <hip/hip_runtime.h>
#include <hip/hip_bf16.h>
#include <cstdint>
#include <cstddef>

typedef unsigned short u16;
typedef __bf16 bf16x8 __attribute__((ext_vector_type(8)));
typedef float f32x4 __attribute__((ext_vector_type(4)));

#define EPSF 1e-5f

__device__ __forceinline__ float b2f(u16 u) {
  unsigned int i = ((unsigned int)u) << 16;
  return __builtin_bit_cast(float, i);
}
__device__ __forceinline__ u16 f2b(float f) {
  unsigned int u = __builtin_bit_cast(unsigned int, f);
  u = u + 0x7fffu + ((u >> 16) & 1u);  // round-to-nearest-even
  return (u16)(u >> 16);
}

// async global->LDS, 16B/lane.
__device__ __forceinline__ void async_load16(const u16* g, u16* l) {
  __builtin_amdgcn_global_load_lds(
      (__attribute__((address_space(1))) void*)(g),
      (__attribute__((address_space(3))) void*)(l), 16, 0, 0);
}

// ---------------- kernel 0: input dtype detection --------------------------
__global__ __launch_bounds__(256) void detect_kernel(const u16* __restrict__ Xu,
                                                     int* __restrict__ flag) {
  int bad = 0;
  for (int i = threadIdx.x; i < 4096; i += 256) {
    float a = fabsf(b2f(Xu[i]));
    if (!(a <= 1e4f)) bad = 1;  // catches huge AND NaN
  }
  if (bad) atomicOr(flag, 1);
}

// ---------------- kernel 1: A -> bf16 (Abf), dual dtype --------------------
__global__ __launch_bounds__(256) void convertA_kernel(const void* __restrict__ A,
                                                       u16* __restrict__ Abf,
                                                       const int* __restrict__ flag) {
  const int isf32 = *flag;
  const size_t i = (size_t)blockIdx.x * 256 + threadIdx.x;  // 8 elems each
  if (isf32) {
    const float4* Af = (const float4*)A;
    float4 a = Af[i * 2], b = Af[i * 2 + 1];
    u16 o[8] = {f2b(a.x), f2b(a.y), f2b(a.z), f2b(a.w),
                f2b(b.x), f2b(b.y), f2b(b.z), f2b(b.w)};
    *(uint4*)(Abf + i * 8) = *(const uint4*)o;
  } else {
    *(uint4*)(Abf + i * 8) = ((const uint4*)A)[i];
  }
}

// ---------------- kernel 2: build F^T [12288][2048] bf16 -------------------
// v2: block = (b, ch, m-chunk). X slab [256 m][12 p] read fully coalesced
// (float4), staged in LDS [256][13] (odd stride -> conflict-free reads),
// then 96 coalesced 512B Ft stores per (f,p). Kills the 12x strided-read
// inflation of v1.
__global__ __launch_bounds__(256) void build_f_kernel(const void* __restrict__ X,
                                                      u16* __restrict__ Ft,
                                                      const int* __restrict__ flag) {
  __shared__ float Xl[256 * 13];
  const int isf32 = *flag;
  const int blk = blockIdx.x;      // b*256 + ch*8 + mc
  const int mc = blk & 7;
  const int ch = (blk >> 3) & 31;
  const int b  = blk >> 8;
  const int tid = threadIdx.x;
  const size_t g0 = ((size_t)(b * 32 + ch) * 2048 + (size_t)mc * 256) * 12;
  if (isf32) {
    const float4* Xg = (const float4*)((const float*)X + g0);
#pragma unroll
    for (int q = 0; q < 3; ++q) {
      const int id = q * 256 + tid;        // 0..767 float4s
      const float4 v = Xg[id];
      const int j = id * 4, row = j / 12, col = j % 12;  // col in {0,4,8}
      Xl[row * 13 + col]     = v.x;
      Xl[row * 13 + col + 1] = v.y;
      Xl[row * 13 + col + 2] = v.z;
      Xl[row * 13 + col + 3] = v.w;
    }
  } else {
    const u16* Xg = (const u16*)X + g0;
#pragma unroll
    for (int q = 0; q < 12; ++q) {
      const int id = q * 256 + tid;        // 0..3071 u16s
      Xl[(id / 12) * 13 + id % 12] = b2f(Xg[id]);
    }
  }
  __syncthreads();
  const int m = tid;
  const int gm = mc * 256 + m;
#pragma unroll
  for (int p = 0; p < 12; ++p) {
    const float x = Xl[m * 13 + p];
    const float x2 = x * x, x3 = x2 * x, x4 = x2 * x2;
    const float e = __expf(x), en = __expf(-x);
    const float vals[8] = {x, x2, x3, x4, x * e, e, x * en, en};
    const size_t cb = (size_t)(b * 12 + p) * 256 + ch;
#pragma unroll
    for (int f = 0; f < 8; ++f)
      Ft[(cb + (size_t)f * 32) * 2048 + gm] = f2b(vals[f]);
  }
}

// ---------------- kernel 3: degree / log-degree / sum(logd) ----------------
__global__ __launch_bounds__(256) void deg_kernel(const u16* __restrict__ Abf,
                                                  float* __restrict__ deg,
                                                  float* __restrict__ logd,
                                                  float* __restrict__ dsum) {
  const int i = blockIdx.x;
  const int tid = threadIdx.x;
  const u16* row = Abf + (size_t)i * 2048;
  float s = 0.f;
  for (int j = tid; j < 2048; j += 256) s += b2f(row[j]);
#pragma unroll
  for (int off = 32; off > 0; off >>= 1) s += __shfl_down(s, off, 64);
  __shared__ float red[4];
  const int lane = tid & 63, w = tid >> 6;
  if (lane == 0) red[w] = s;
  __syncthreads();
  if (tid == 0) {
    float t = red[0] + red[1] + red[2] + red[3];
    deg[i] = t;
    float ld = logf(t + 1.f);
    logd[i] = ld;
    atomicAdd(dsum, ld);
  }
}

// ---------------- kernel 4: Theta transpose -> ThT [32][672] ---------------
__global__ __launch_bounds__(256) void thetaT_kernel(const void* __restrict__ Th,
                                                     u16* __restrict__ ThT,
                                                     const int* __restrict__ flag) {
  const int isf32 = *flag;
  const int e = blockIdx.x * 256 + threadIdx.x;
  if (e < 21504) {
    const int k = e >> 5, o = e & 31;
    ThT[o * 672 + k] = isf32 ? f2b(((const float*)Th)[e]) : ((const u16*)Th)[e];
  }
}

// ---------------- kernel 5: GEMM Y = Abf @ F (m97 async + swizzle) ---------
// M=2048 (i), N=12288 (col), K=2048 (m). Abf row-major [M][K], Ft = B^T [N][K].
// LDS chunk-swizzled; C staged via LDS for full-line coalesced Y writes.
// FROZEN from round 3 (129 us, 800 TF, WRITE ideal).
__global__ __launch_bounds__(256) void gemm_kernel(const u16* __restrict__ A,
                                                   const u16* __restrict__ Ft,
                                                   u16* __restrict__ Y) {
  __shared__ __attribute__((aligned(16))) u16 smem[2 * 128 * 64];  // 32 KB
  u16* As = smem;             // [128][64]
  u16* Bs = smem + 128 * 64;  // [128][64]
  const int tid = threadIdx.x;
  const int wave = tid >> 6;
  const int lane = tid & 63;
  const int l15 = lane & 15;
  const int quad = lane >> 4;
  const int wm = wave >> 1;
  const int wn = wave & 1;

  const int f = blockIdx.x;          // 0..1535
  const int xcd = f & 7;
  const int jj = f >> 3;             // 0..191
  const int bm = xcd * 2 + (jj >= 96 ? 1 : 0);
  const int bn = jj % 96;

  const int lrow = lane >> 3;                    // 0..7
  const int schunk = (lane & 7) ^ lrow;          // swizzled source chunk
  const u16* gA = A  + (size_t)(bm * 128 + wave * 32 + lrow) * 2048 + schunk * 8;
  const u16* gB = Ft + (size_t)(bn * 128 + wave * 32 + lrow) * 2048 + schunk * 8;
  u16* lA = As + wave * 32 * 64 + lane * 8;  // per-lane dest (base + lane*16B)
  u16* lB = Bs + wave * 32 * 64 + lane * 8;

  f32x4 acc[4][4];
#pragma unroll
  for (int i = 0; i < 4; ++i)
#pragma unroll
    for (int j = 0; j < 4; ++j) acc[i][j] = (f32x4){0.f, 0.f, 0.f, 0.f};

  for (int kk = 0; kk < 2048; kk += 64) {
    __syncthreads();  // prev iter's LDS reads done before overwrite
#pragma unroll
    for (int i = 0; i < 4; ++i) {
      async_load16(gA + (size_t)i * (8 * 2048) + kk, lA + i * (8 * 64));
      async_load16(gB + (size_t)i * (8 * 2048) + kk, lB + i * (8 * 64));
    }
    __syncthreads();  // compiler drains vmcnt(0) before s_barrier
#pragma unroll
    for (int ks = 0; ks < 2; ++ks) {
      const int ca = ((ks * 4 + quad) ^ (l15 & 7)) * 8;  // un-swizzle chunk
      bf16x8 af[4], bfr[4];
#pragma unroll
      for (int t = 0; t < 4; ++t)
        af[t] = *(const bf16x8*)(As + (wm * 64 + t * 16 + l15) * 64 + ca);
#pragma unroll
      for (int t = 0; t < 4; ++t)
        bfr[t] = *(const bf16x8*)(Bs + (wn * 64 + t * 16 + l15) * 64 + ca);
#pragma unroll
      for (int mt = 0; mt < 4; ++mt)
#pragma unroll
        for (int nt = 0; nt < 4; ++nt)
          acc[mt][nt] = __builtin_amdgcn_mfma_f32_16x16x32_bf16(af[mt], bfr[nt],
                                                                acc[mt][nt], 0, 0, 0);
    }
  }

  // ---- C epilogue: stage bf16 C-tile in LDS (aliases As/Bs), write 16B/lane
  __syncthreads();  // all K-loop LDS reads complete before aliasing
  u16* Cs = smem;   // [128][128] u16 = 32 KB
#pragma unroll
  for (int mt = 0; mt < 4; ++mt)
#pragma unroll
    for (int nt = 0; nt < 4; ++nt) {
      const int row = wm * 64 + mt * 16 + quad * 4;
      const int col = wn * 64 + nt * 16 + l15;
#pragma unroll
      for (int j = 0; j < 4; ++j)
        Cs[(row + j) * 128 + col] = f2b(acc[mt][nt][j]);
    }
  __syncthreads();
  const size_t ybase = (size_t)(bm * 128) * 12288 + (size_t)bn * 128;
#pragma unroll
  for (int q = 0; q < 8; ++q) {
    const int id = q * 256 + tid;           // 0..2047
    const int r = id >> 4, c = (id & 15) * 8;
    *(uint4*)(Y + ybase + (size_t)r * 12288 + c) = *(const uint4*)(Cs + r * 128 + c);
  }
}

// ---------------- kernel 6: epilogue (features + MFMA projection) ----------
// v2: self-x read from Ft's identity feature (f=0 row block) -> coalesced,
// no strided X pass. Everything else unchanged.
__global__ __launch_bounds__(256) void epilogue_kernel(
    const u16* __restrict__ Y, const u16* __restrict__ Fx,
    const float* __restrict__ deg, const float* __restrict__ logd,
    const float* __restrict__ dsum, const u16* __restrict__ ThT,
    const void* __restrict__ Bias, void* __restrict__ out,
    const int* __restrict__ flag) {
  __shared__ __attribute__((aligned(16))) u16 feats[32 * 680];
  const int isf32 = *flag;
  const int tid = threadIdx.x;
  const int nc = blockIdx.x;   // 0..63 node chunk
  const int bp = blockIdx.y;   // 0..47
  const int b = bp / 12, p = bp % 12;
  const float delta = dsum[0] * (1.0f / 2048.0f);

  const int nl = tid >> 3;     // 0..31 local node
  const int chg = tid & 7;     // 4 channels each
  const int i = nc * 32 + nl;
  const float d = fmaxf(deg[i], EPSF);
  const float s = logd[i] / delta;
  const float is = 1.0f / fmaxf(s, EPSF);
  const u16* yrow = Y + (size_t)i * 12288 + (size_t)bp * 256;
#pragma unroll
  for (int cc = 0; cc < 4; ++cc) {
    const int ch = chg * 4 + cc;
    const float m1 = b2f(yrow[ch]) / d;
    const float m2 = b2f(yrow[32 + ch]) / d;
    const float m3 = b2f(yrow[64 + ch]) / d;
    const float m4 = b2f(yrow[96 + ch]) / d;
    const float smx = b2f(yrow[128 + ch]) / (b2f(yrow[160 + ch]) + EPSF);
    const float smn = b2f(yrow[192 + ch]) / (b2f(yrow[224 + ch]) + EPSF);
    const float x = b2f(Fx[(size_t)(bp * 256 + ch) * 2048 + i]);  // identity feat
    const float var = fmaxf(m2 - m1 * m1, 0.f);
    const float stdv = sqrtf(var + EPSF);
    const float x2 = x * x, x3 = x2 * x, x4 = x2 * x2;
    const float dist = x2 - 2.f * x * m1 + m2;
    const float ed2 = x4 - 4.f * x3 * m1 + 6.f * x2 * m2 - 4.f * x * m3 + m4;
    const float dstd = sqrtf(fmaxf(ed2 - dist * dist, 0.f) + EPSF);
    const float f7[7] = {smn, smx, m1, stdv, var, dist, dstd};
#pragma unroll
    for (int a = 0; a < 7; ++a) {
      const int k = a * 32 + ch;
      feats[nl * 680 + k]       = f2b(f7[a]);
      feats[nl * 680 + 224 + k] = f2b(f7[a] * s);
      feats[nl * 680 + 448 + k] = f2b(f7[a] * is);
    }
  }
  __syncthreads();

  const int wave = tid >> 6, lane = tid & 63;
  const int l15 = lane & 15, quad = lane >> 4;
  const int mt = wave >> 1, nt = wave & 1;  // 2x2 of 16x16
  f32x4 acc = (f32x4){0.f, 0.f, 0.f, 0.f};
#pragma unroll
  for (int kt = 0; kt < 21; ++kt) {  // K = 672
    bf16x8 a  = *(const bf16x8*)(feats + (mt * 16 + l15) * 680 + kt * 32 + quad * 8);
    bf16x8 bb = *(const bf16x8*)(ThT + (size_t)(nt * 16 + l15) * 672 + kt * 32 + quad * 8);
    acc = __builtin_amdgcn_mfma_f32_16x16x32_bf16(a, bb, acc, 0, 0, 0);
  }
#pragma unroll
  for (int j = 0; j < 4; ++j) {
    const int node = mt * 16 + quad * 4 + j;
    const int o = nt * 16 + l15;
    const float bias = isf32 ? ((const float*)Bias)[o] : b2f(((const u16*)Bias)[o]);
    float v = acc[j] + bias;
    v = v > 0.f ? v : 0.01f * v;   // leaky_relu
    const int ig = nc * 32 + node;
    const size_t oi = ((size_t)(b * 32 + o) * 2048 + ig) * 12 + p;
    if (isf32) ((float*)out)[oi] = v;       // fp32 dataset -> fp32 output
    else       ((u16*)out)[oi]   = f2b(v);  // bf16 dataset -> bf16 output
  }
}

// ---------------------------------------------------------------------------
extern "C" void kernel_launch(void* const* d_in, const int* in_sizes, int n_in,
                              void* d_out, int out_size, void* d_ws, size_t ws_size,
                              hipStream_t stream) {
  const void* X    = d_in[0];
  const void* A    = d_in[1];
  const void* Th   = d_in[2];
  const void* Bias = d_in[3];
  char* ws = (char*)d_ws;

  // workspace layout (bytes): ~109 MB total
  u16*   Ft   = (u16*)(ws);                       // 12288*2048*2 = 50331648
  u16*   Y    = (u16*)(ws + 50331648);            // 2048*12288*2 = 50331648
  u16*   Abf  = (u16*)(ws + 100663296);           // 2048*2048*2  = 8388608
  float* deg  = (float*)(ws + 109051904);         // 8192
  float* logd = (float*)(ws + 109060096);         // 8192
  u16*   ThT  = (u16*)(ws + 109068288);           // 43008
  float* dsum = (float*)(ws + 109111296);         // 4
  int*   flag = (int*)(ws + 109111300);           // 4

  hipMemsetAsync(dsum, 0, 8, stream);  // zeroes dsum + flag
  detect_kernel<<<1, 256, 0, stream>>>((const u16*)X, flag);
  convertA_kernel<<<2048, 256, 0, stream>>>(A, Abf, flag);
  build_f_kernel<<<1024, 256, 0, stream>>>(X, Ft, flag);
  deg_kernel<<<2048, 256, 0, stream>>>(Abf, deg, logd, dsum);
  thetaT_kernel<<<84, 256, 0, stream>>>(Th, ThT, flag);
  gemm_kernel<<<1536, 256, 0, stream>>>(Abf, Ft, Y);
  epilogue_kernel<<<dim3(64, 48), 256, 0, stream>>>(Y, Ft, deg, logd, dsum, ThT, Bias, d_out, flag);
}

// Round 6
// 276.693 us; speedup vs baseline: 2.2185x; 1.0254x over previous
//
#include <hip/hip_runtime.h>
#include <hip/hip_bf16.h>
#include <cstdint>
#include <cstddef>

typedef unsigned short u16;
typedef __bf16 bf16x8 __attribute__((ext_vector_type(8)));
typedef float f32x4 __attribute__((ext_vector_type(4)));

#define EPSF 1e-5f

__device__ __forceinline__ float b2f(u16 u) {
  unsigned int i = ((unsigned int)u) << 16;
  return __builtin_bit_cast(float, i);
}
__device__ __forceinline__ u16 f2b(float f) {
  unsigned int u = __builtin_bit_cast(unsigned int, f);
  u = u + 0x7fffu + ((u >> 16) & 1u);  // round-to-nearest-even
  return (u16)(u >> 16);
}

// async global->LDS, 16B/lane.
__device__ __forceinline__ void async_load16(const u16* g, u16* l) {
  __builtin_amdgcn_global_load_lds(
      (__attribute__((address_space(1))) void*)(g),
      (__attribute__((address_space(3))) void*)(l), 16, 0, 0);
}

// ---------------- kernel 0: input dtype detection --------------------------
__global__ __launch_bounds__(256) void detect_kernel(const u16* __restrict__ Xu,
                                                     int* __restrict__ flag) {
  int bad = 0;
  for (int i = threadIdx.x; i < 4096; i += 256) {
    float a = fabsf(b2f(Xu[i]));
    if (!(a <= 1e4f)) bad = 1;  // catches huge AND NaN
  }
  if (bad) atomicOr(flag, 1);
}

// ---------------- kernel 1: A -> bf16 (Abf), dual dtype --------------------
__global__ __launch_bounds__(256) void convertA_kernel(const void* __restrict__ A,
                                                       u16* __restrict__ Abf,
                                                       const int* __restrict__ flag) {
  const int isf32 = *flag;
  const size_t i = (size_t)blockIdx.x * 256 + threadIdx.x;  // 8 elems each
  if (isf32) {
    const float4* Af = (const float4*)A;
    float4 a = Af[i * 2], b = Af[i * 2 + 1];
    u16 o[8] = {f2b(a.x), f2b(a.y), f2b(a.z), f2b(a.w),
                f2b(b.x), f2b(b.y), f2b(b.z), f2b(b.w)};
    *(uint4*)(Abf + i * 8) = *(const uint4*)o;
  } else {
    *(uint4*)(Abf + i * 8) = ((const uint4*)A)[i];
  }
}

// ---------------- kernel 2: build F^T [12288][2048] bf16 (FROZEN r4) -------
__global__ __launch_bounds__(256) void build_f_kernel(const void* __restrict__ X,
                                                      u16* __restrict__ Ft,
                                                      const int* __restrict__ flag) {
  __shared__ float Xl[256 * 13];
  const int isf32 = *flag;
  const int blk = blockIdx.x;      // b*256 + ch*8 + mc
  const int mc = blk & 7;
  const int ch = (blk >> 3) & 31;
  const int b  = blk >> 8;
  const int tid = threadIdx.x;
  const size_t g0 = ((size_t)(b * 32 + ch) * 2048 + (size_t)mc * 256) * 12;
  if (isf32) {
    const float4* Xg = (const float4*)((const float*)X + g0);
#pragma unroll
    for (int q = 0; q < 3; ++q) {
      const int id = q * 256 + tid;        // 0..767 float4s
      const float4 v = Xg[id];
      const int j = id * 4, row = j / 12, col = j % 12;  // col in {0,4,8}
      Xl[row * 13 + col]     = v.x;
      Xl[row * 13 + col + 1] = v.y;
      Xl[row * 13 + col + 2] = v.z;
      Xl[row * 13 + col + 3] = v.w;
    }
  } else {
    const u16* Xg = (const u16*)X + g0;
#pragma unroll
    for (int q = 0; q < 12; ++q) {
      const int id = q * 256 + tid;        // 0..3071 u16s
      Xl[(id / 12) * 13 + id % 12] = b2f(Xg[id]);
    }
  }
  __syncthreads();
  const int m = tid;
  const int gm = mc * 256 + m;
#pragma unroll
  for (int p = 0; p < 12; ++p) {
    const float x = Xl[m * 13 + p];
    const float x2 = x * x, x3 = x2 * x, x4 = x2 * x2;
    const float e = __expf(x), en = __expf(-x);
    const float vals[8] = {x, x2, x3, x4, x * e, e, x * en, en};
    const size_t cb = (size_t)(b * 12 + p) * 256 + ch;
#pragma unroll
    for (int f = 0; f < 8; ++f)
      Ft[(cb + (size_t)f * 32) * 2048 + gm] = f2b(vals[f]);
  }
}

// ---------------- kernel 3: degree / log-degree / sum(logd) ----------------
__global__ __launch_bounds__(256) void deg_kernel(const u16* __restrict__ Abf,
                                                  float* __restrict__ deg,
                                                  float* __restrict__ logd,
                                                  float* __restrict__ dsum) {
  const int i = blockIdx.x;
  const int tid = threadIdx.x;
  const u16* row = Abf + (size_t)i * 2048;
  float s = 0.f;
  for (int j = tid; j < 2048; j += 256) s += b2f(row[j]);
#pragma unroll
  for (int off = 32; off > 0; off >>= 1) s += __shfl_down(s, off, 64);
  __shared__ float red[4];
  const int lane = tid & 63, w = tid >> 6;
  if (lane == 0) red[w] = s;
  __syncthreads();
  if (tid == 0) {
    float t = red[0] + red[1] + red[2] + red[3];
    deg[i] = t;
    float ld = logf(t + 1.f);
    logd[i] = ld;
    atomicAdd(dsum, ld);
  }
}

// ---------------- kernel 4: Theta transpose -> ThT [32][672] ---------------
__global__ __launch_bounds__(256) void thetaT_kernel(const void* __restrict__ Th,
                                                     u16* __restrict__ ThT,
                                                     const int* __restrict__ flag) {
  const int isf32 = *flag;
  const int e = blockIdx.x * 256 + threadIdx.x;
  if (e < 21504) {
    const int k = e >> 5, o = e & 31;
    ThT[o * 672 + k] = isf32 ? f2b(((const float*)Th)[e]) : ((const u16*)Th)[e];
  }
}

// ---------------- kernel 5: GEMM Y = Abf @ F (FROZEN r3: 125us, ~800TF) ----
__global__ __launch_bounds__(256) void gemm_kernel(const u16* __restrict__ A,
                                                   const u16* __restrict__ Ft,
                                                   u16* __restrict__ Y) {
  __shared__ __attribute__((aligned(16))) u16 smem[2 * 128 * 64];  // 32 KB
  u16* As = smem;             // [128][64]
  u16* Bs = smem + 128 * 64;  // [128][64]
  const int tid = threadIdx.x;
  const int wave = tid >> 6;
  const int lane = tid & 63;
  const int l15 = lane & 15;
  const int quad = lane >> 4;
  const int wm = wave >> 1;
  const int wn = wave & 1;

  const int f = blockIdx.x;          // 0..1535
  const int xcd = f & 7;
  const int jj = f >> 3;             // 0..191
  const int bm = xcd * 2 + (jj >= 96 ? 1 : 0);
  const int bn = jj % 96;

  const int lrow = lane >> 3;                    // 0..7
  const int schunk = (lane & 7) ^ lrow;          // swizzled source chunk
  const u16* gA = A  + (size_t)(bm * 128 + wave * 32 + lrow) * 2048 + schunk * 8;
  const u16* gB = Ft + (size_t)(bn * 128 + wave * 32 + lrow) * 2048 + schunk * 8;
  u16* lA = As + wave * 32 * 64 + lane * 8;  // per-lane dest (base + lane*16B)
  u16* lB = Bs + wave * 32 * 64 + lane * 8;

  f32x4 acc[4][4];
#pragma unroll
  for (int i = 0; i < 4; ++i)
#pragma unroll
    for (int j = 0; j < 4; ++j) acc[i][j] = (f32x4){0.f, 0.f, 0.f, 0.f};

  for (int kk = 0; kk < 2048; kk += 64) {
    __syncthreads();  // prev iter's LDS reads done before overwrite
#pragma unroll
    for (int i = 0; i < 4; ++i) {
      async_load16(gA + (size_t)i * (8 * 2048) + kk, lA + i * (8 * 64));
      async_load16(gB + (size_t)i * (8 * 2048) + kk, lB + i * (8 * 64));
    }
    __syncthreads();  // compiler drains vmcnt(0) before s_barrier
#pragma unroll
    for (int ks = 0; ks < 2; ++ks) {
      const int ca = ((ks * 4 + quad) ^ (l15 & 7)) * 8;  // un-swizzle chunk
      bf16x8 af[4], bfr[4];
#pragma unroll
      for (int t = 0; t < 4; ++t)
        af[t] = *(const bf16x8*)(As + (wm * 64 + t * 16 + l15) * 64 + ca);
#pragma unroll
      for (int t = 0; t < 4; ++t)
        bfr[t] = *(const bf16x8*)(Bs + (wn * 64 + t * 16 + l15) * 64 + ca);
#pragma unroll
      for (int mt = 0; mt < 4; ++mt)
#pragma unroll
        for (int nt = 0; nt < 4; ++nt)
          acc[mt][nt] = __builtin_amdgcn_mfma_f32_16x16x32_bf16(af[mt], bfr[nt],
                                                                acc[mt][nt], 0, 0, 0);
    }
  }

  __syncthreads();  // all K-loop LDS reads complete before aliasing
  u16* Cs = smem;   // [128][128] u16 = 32 KB
#pragma unroll
  for (int mt = 0; mt < 4; ++mt)
#pragma unroll
    for (int nt = 0; nt < 4; ++nt) {
      const int row = wm * 64 + mt * 16 + quad * 4;
      const int col = wn * 64 + nt * 16 + l15;
#pragma unroll
      for (int j = 0; j < 4; ++j)
        Cs[(row + j) * 128 + col] = f2b(acc[mt][nt][j]);
    }
  __syncthreads();
  const size_t ybase = (size_t)(bm * 128) * 12288 + (size_t)bn * 128;
#pragma unroll
  for (int q = 0; q < 8; ++q) {
    const int id = q * 256 + tid;           // 0..2047
    const int r = id >> 4, c = (id & 15) * 8;
    *(uint4*)(Y + ybase + (size_t)r * 12288 + c) = *(const uint4*)(Cs + r * 128 + c);
  }
}

// ---------------- kernel 6: epilogue v3 ------------------------------------
// block = (nc: 32 nodes, b, pz: 6 p's). p-loop inside: Y rows staged to LDS
// coalesced (uint4); self-x staged coalesced; per-thread (node,o) results
// accumulated over 6 p's in regs -> one contiguous 24B store (3x float2).
// Kills: scattered global Y/Fx scalar loads + 48B-stride out writes.
__global__ __launch_bounds__(256) void epilogue_kernel(
    const u16* __restrict__ Y, const u16* __restrict__ Fx,
    const float* __restrict__ deg, const float* __restrict__ logd,
    const float* __restrict__ dsum, const u16* __restrict__ ThT,
    const void* __restrict__ Bias, void* __restrict__ out,
    const int* __restrict__ flag) {
  __shared__ __attribute__((aligned(16))) u16 Ys[32 * 264];   // 16.5 KB (264*2=528, 16B-mult)
  __shared__ u16 Xs[32 * 33];                                 // 2.1 KB
  __shared__ __attribute__((aligned(16))) u16 feats[32 * 680];// 42.5 KB
  const int isf32 = *flag;
  const int tid = threadIdx.x;
  const int nc = blockIdx.x;   // 0..63 node chunk
  const int b  = blockIdx.y;   // 0..3
  const int pz = blockIdx.z;   // 0..1
  const float delta = dsum[0] * (1.0f / 2048.0f);

  // phase-1 identity
  const int nl = tid >> 3;     // 0..31 local node
  const int chg = tid & 7;     // 4 channels each
  const int inode = nc * 32 + nl;
  const float d = fmaxf(deg[inode], EPSF);
  const float rd = 1.0f / d;
  const float s = logd[inode] / delta;
  const float is = 1.0f / fmaxf(s, EPSF);

  // phase-2 identity
  const int wave = tid >> 6, lane = tid & 63;
  const int l15 = lane & 15, quad = lane >> 4;
  const int mt = wave >> 1, nt = wave & 1;  // 2x2 of 16x16
  const int o = nt * 16 + l15;
  const float bias = isf32 ? ((const float*)Bias)[o] : b2f(((const u16*)Bias)[o]);

  float r[4][6];

#pragma unroll
  for (int pp = 0; pp < 6; ++pp) {
    const int p = pz * 6 + pp;
    const int bp = b * 12 + p;
    __syncthreads();  // prior iter's LDS reads complete
    // stage Y rows [32 nodes][256] and self-x [32 ch][32 nodes]
#pragma unroll
    for (int q = 0; q < 4; ++q) {
      const int id = q * 256 + tid;                 // 0..1023
      const int rr = id >> 5, ck = id & 31;
      *(uint4*)(Ys + rr * 264 + ck * 8) =
          *(const uint4*)(Y + (size_t)(nc * 32 + rr) * 12288 + (size_t)bp * 256 + ck * 8);
      Xs[rr * 33 + ck] = Fx[(size_t)(bp * 256 + rr) * 2048 + nc * 32 + ck];
    }
    __syncthreads();

    const u16* yr = Ys + nl * 264;
#pragma unroll
    for (int cc = 0; cc < 4; ++cc) {
      const int ch = chg * 4 + cc;
      const float m1 = b2f(yr[ch]) * rd;
      const float m2 = b2f(yr[32 + ch]) * rd;
      const float m3 = b2f(yr[64 + ch]) * rd;
      const float m4 = b2f(yr[96 + ch]) * rd;
      const float smx = b2f(yr[128 + ch]) / (b2f(yr[160 + ch]) + EPSF);
      const float smn = b2f(yr[192 + ch]) / (b2f(yr[224 + ch]) + EPSF);
      const float x = b2f(Xs[ch * 33 + nl]);
      const float var = fmaxf(m2 - m1 * m1, 0.f);
      const float stdv = sqrtf(var + EPSF);
      const float x2 = x * x, x3 = x2 * x, x4 = x2 * x2;
      const float dist = x2 - 2.f * x * m1 + m2;
      const float ed2 = x4 - 4.f * x3 * m1 + 6.f * x2 * m2 - 4.f * x * m3 + m4;
      const float dstd = sqrtf(fmaxf(ed2 - dist * dist, 0.f) + EPSF);
      const float f7[7] = {smn, smx, m1, stdv, var, dist, dstd};
#pragma unroll
      for (int a = 0; a < 7; ++a) {
        const int k = a * 32 + ch;
        feats[nl * 680 + k]       = f2b(f7[a]);
        feats[nl * 680 + 224 + k] = f2b(f7[a] * s);
        feats[nl * 680 + 448 + k] = f2b(f7[a] * is);
      }
    }
    __syncthreads();

    f32x4 acc = (f32x4){0.f, 0.f, 0.f, 0.f};
#pragma unroll
    for (int kt = 0; kt < 21; ++kt) {  // K = 672
      bf16x8 a  = *(const bf16x8*)(feats + (mt * 16 + l15) * 680 + kt * 32 + quad * 8);
      bf16x8 bb = *(const bf16x8*)(ThT + (size_t)o * 672 + kt * 32 + quad * 8);
      acc = __builtin_amdgcn_mfma_f32_16x16x32_bf16(a, bb, acc, 0, 0, 0);
    }
#pragma unroll
    for (int j = 0; j < 4; ++j) r[j][pp] = acc[j];
  }

  // final store: per (node,o): 6 contiguous p's = 24 B
#pragma unroll
  for (int j = 0; j < 4; ++j) {
    const int node = mt * 16 + quad * 4 + j;
    const int ig = nc * 32 + node;
    const size_t oi = ((size_t)(b * 32 + o) * 2048 + ig) * 12 + pz * 6;
    float v[6];
#pragma unroll
    for (int k = 0; k < 6; ++k) {
      float t = r[j][k] + bias;
      v[k] = t > 0.f ? t : 0.01f * t;   // leaky_relu
    }
    if (isf32) {
      float* dst = (float*)out + oi;   // 8B-aligned (oi = 12a + 6pz, even)
      *(float2*)(dst)     = (float2){v[0], v[1]};
      *(float2*)(dst + 2) = (float2){v[2], v[3]};
      *(float2*)(dst + 4) = (float2){v[4], v[5]};
    } else {
      u16* dst = (u16*)out + oi;
#pragma unroll
      for (int k = 0; k < 6; ++k) dst[k] = f2b(v[k]);
    }
  }
}

// ---------------------------------------------------------------------------
extern "C" void kernel_launch(void* const* d_in, const int* in_sizes, int n_in,
                              void* d_out, int out_size, void* d_ws, size_t ws_size,
                              hipStream_t stream) {
  const void* X    = d_in[0];
  const void* A    = d_in[1];
  const void* Th   = d_in[2];
  const void* Bias = d_in[3];
  char* ws = (char*)d_ws;

  // workspace layout (bytes): ~109 MB total
  u16*   Ft   = (u16*)(ws);                       // 12288*2048*2 = 50331648
  u16*   Y    = (u16*)(ws + 50331648);            // 2048*12288*2 = 50331648
  u16*   Abf  = (u16*)(ws + 100663296);           // 2048*2048*2  = 8388608
  float* deg  = (float*)(ws + 109051904);         // 8192
  float* logd = (float*)(ws + 109060096);         // 8192
  u16*   ThT  = (u16*)(ws + 109068288);           // 43008
  float* dsum = (float*)(ws + 109111296);         // 4
  int*   flag = (int*)(ws + 109111300);           // 4

  hipMemsetAsync(dsum, 0, 8, stream);  // zeroes dsum + flag
  detect_kernel<<<1, 256, 0, stream>>>((const u16*)X, flag);
  convertA_kernel<<<2048, 256, 0, stream>>>(A, Abf, flag);
  build_f_kernel<<<1024, 256, 0, stream>>>(X, Ft, flag);
  deg_kernel<<<2048, 256, 0, stream>>>(Abf, deg, logd, dsum);
  thetaT_kernel<<<84, 256, 0, stream>>>(Th, ThT, flag);
  gemm_kernel<<<1536, 256, 0, stream>>>(Abf, Ft, Y);
  epilogue_kernel<<<dim3(64, 4, 2), 256, 0, stream>>>(Y, Ft, deg, logd, dsum, ThT, Bias, d_out, flag);
}

// Round 7
// 263.812 us; speedup vs baseline: 2.3268x; 1.0488x over previous
//
#include <hip/hip_runtime.h>
#include <hip/hip_bf16.h>
#include <cstdint>
#include <cstddef>

typedef unsigned short u16;
typedef __bf16 bf16x8 __attribute__((ext_vector_type(8)));
typedef float f32x4 __attribute__((ext_vector_type(4)));

#define EPSF 1e-5f

__device__ __forceinline__ float b2f(u16 u) {
  unsigned int i = ((unsigned int)u) << 16;
  return __builtin_bit_cast(float, i);
}
__device__ __forceinline__ u16 f2b(float f) {
  unsigned int u = __builtin_bit_cast(unsigned int, f);
  u = u + 0x7fffu + ((u >> 16) & 1u);  // round-to-nearest-even
  return (u16)(u >> 16);
}

// async global->LDS, 16B/lane.
__device__ __forceinline__ void async_load16(const u16* g, u16* l) {
  __builtin_amdgcn_global_load_lds(
      (__attribute__((address_space(1))) void*)(g),
      (__attribute__((address_space(3))) void*)(l), 16, 0, 0);
}

// ---------------- kernel 1: fused prep (A-convert+deg | build_f | thetaT) --
// Role-switched by blockIdx to cut graph-node count 9 -> 4. Dtype detection
// is per-block (scan X's first 2048 u16 as bf16: fp32 storage guarantees a
// |v|>1e4/NaN among the low-mantissa words; true-bf16 N(0,1) never exceeds 6).
__global__ __launch_bounds__(256) void prep_kernel(
    const void* __restrict__ X, const void* __restrict__ A,
    const void* __restrict__ Th, u16* __restrict__ Abf, u16* __restrict__ Ft,
    float* __restrict__ deg, float* __restrict__ logd,
    float* __restrict__ dsum, u16* __restrict__ ThT) {
  __shared__ int sbad;
  __shared__ float Xl[256 * 13];
  __shared__ float red[4];
  const int tid = threadIdx.x;
  if (tid == 0) sbad = 0;
  __syncthreads();
  {
    const u16* Xu = (const u16*)X;
    int bad = 0;
#pragma unroll
    for (int q = 0; q < 8; ++q) {
      float a = fabsf(b2f(Xu[q * 256 + tid]));
      if (!(a <= 1e4f)) bad = 1;  // huge or NaN
    }
    if (bad) atomicOr(&sbad, 1);
  }
  __syncthreads();
  const int isf32 = sbad;
  const int bid = blockIdx.x;

  if (bid < 2048) {
    // ---- role A: convert A row -> bf16 AND compute degree in one pass
    const int row = bid;
    float s = 0.f;
    uint4 st;
    if (isf32) {
      const float4* Af = (const float4*)A + (size_t)row * 512 + tid * 2;
      float4 a = Af[0], b = Af[1];
      s = a.x + a.y + a.z + a.w + b.x + b.y + b.z + b.w;
      u16 o[8] = {f2b(a.x), f2b(a.y), f2b(a.z), f2b(a.w),
                  f2b(b.x), f2b(b.y), f2b(b.z), f2b(b.w)};
      st = *(const uint4*)o;
    } else {
      st = ((const uint4*)A)[(size_t)row * 256 + tid];
      const u16* o = (const u16*)&st;
#pragma unroll
      for (int k = 0; k < 8; ++k) s += b2f(o[k]);
    }
    *(uint4*)(Abf + (size_t)row * 2048 + tid * 8) = st;
#pragma unroll
    for (int off = 32; off > 0; off >>= 1) s += __shfl_down(s, off, 64);
    const int lane = tid & 63, w = tid >> 6;
    if (lane == 0) red[w] = s;
    __syncthreads();
    if (tid == 0) {
      float t = red[0] + red[1] + red[2] + red[3];
      deg[row] = t;
      float ld = logf(t + 1.f);
      logd[row] = ld;
      atomicAdd(dsum, ld);
    }
  } else if (bid < 3072) {
    // ---- role B: build F^T [12288][2048] bf16 (r4 logic)
    const int blk = bid - 2048;      // b*256 + ch*8 + mc
    const int mc = blk & 7;
    const int ch = (blk >> 3) & 31;
    const int b  = blk >> 8;
    const size_t g0 = ((size_t)(b * 32 + ch) * 2048 + (size_t)mc * 256) * 12;
    if (isf32) {
      const float4* Xg = (const float4*)((const float*)X + g0);
#pragma unroll
      for (int q = 0; q < 3; ++q) {
        const int id = q * 256 + tid;        // 0..767 float4s
        const float4 v = Xg[id];
        const int j = id * 4, row = j / 12, col = j % 12;  // col in {0,4,8}
        Xl[row * 13 + col]     = v.x;
        Xl[row * 13 + col + 1] = v.y;
        Xl[row * 13 + col + 2] = v.z;
        Xl[row * 13 + col + 3] = v.w;
      }
    } else {
      const u16* Xg = (const u16*)X + g0;
#pragma unroll
      for (int q = 0; q < 12; ++q) {
        const int id = q * 256 + tid;        // 0..3071 u16s
        Xl[(id / 12) * 13 + id % 12] = b2f(Xg[id]);
      }
    }
    __syncthreads();
    const int m = tid;
    const int gm = mc * 256 + m;
#pragma unroll
    for (int p = 0; p < 12; ++p) {
      const float x = Xl[m * 13 + p];
      const float x2 = x * x, x3 = x2 * x, x4 = x2 * x2;
      const float e = __expf(x), en = __expf(-x);
      const float vals[8] = {x, x2, x3, x4, x * e, e, x * en, en};
      const size_t cb = (size_t)(b * 12 + p) * 256 + ch;
#pragma unroll
      for (int f = 0; f < 8; ++f)
        Ft[(cb + (size_t)f * 32) * 2048 + gm] = f2b(vals[f]);
    }
  } else {
    // ---- role C: Theta transpose -> ThT [32][672]
    const int e = (bid - 3072) * 256 + tid;
    if (e < 21504) {
      const int k = e >> 5, o = e & 31;
      ThT[o * 672 + k] = isf32 ? f2b(((const float*)Th)[e]) : ((const u16*)Th)[e];
    }
  }
}

// ---------------- kernel 2: GEMM Y = Abf @ F (FROZEN r3: ~122us, ~845TF) ---
__global__ __launch_bounds__(256) void gemm_kernel(const u16* __restrict__ A,
                                                   const u16* __restrict__ Ft,
                                                   u16* __restrict__ Y) {
  __shared__ __attribute__((aligned(16))) u16 smem[2 * 128 * 64];  // 32 KB
  u16* As = smem;             // [128][64]
  u16* Bs = smem + 128 * 64;  // [128][64]
  const int tid = threadIdx.x;
  const int wave = tid >> 6;
  const int lane = tid & 63;
  const int l15 = lane & 15;
  const int quad = lane >> 4;
  const int wm = wave >> 1;
  const int wn = wave & 1;

  const int f = blockIdx.x;          // 0..1535
  const int xcd = f & 7;
  const int jj = f >> 3;             // 0..191
  const int bm = xcd * 2 + (jj >= 96 ? 1 : 0);
  const int bn = jj % 96;

  const int lrow = lane >> 3;                    // 0..7
  const int schunk = (lane & 7) ^ lrow;          // swizzled source chunk
  const u16* gA = A  + (size_t)(bm * 128 + wave * 32 + lrow) * 2048 + schunk * 8;
  const u16* gB = Ft + (size_t)(bn * 128 + wave * 32 + lrow) * 2048 + schunk * 8;
  u16* lA = As + wave * 32 * 64 + lane * 8;  // per-lane dest (base + lane*16B)
  u16* lB = Bs + wave * 32 * 64 + lane * 8;

  f32x4 acc[4][4];
#pragma unroll
  for (int i = 0; i < 4; ++i)
#pragma unroll
    for (int j = 0; j < 4; ++j) acc[i][j] = (f32x4){0.f, 0.f, 0.f, 0.f};

  for (int kk = 0; kk < 2048; kk += 64) {
    __syncthreads();  // prev iter's LDS reads done before overwrite
#pragma unroll
    for (int i = 0; i < 4; ++i) {
      async_load16(gA + (size_t)i * (8 * 2048) + kk, lA + i * (8 * 64));
      async_load16(gB + (size_t)i * (8 * 2048) + kk, lB + i * (8 * 64));
    }
    __syncthreads();  // compiler drains vmcnt(0) before s_barrier
#pragma unroll
    for (int ks = 0; ks < 2; ++ks) {
      const int ca = ((ks * 4 + quad) ^ (l15 & 7)) * 8;  // un-swizzle chunk
      bf16x8 af[4], bfr[4];
#pragma unroll
      for (int t = 0; t < 4; ++t)
        af[t] = *(const bf16x8*)(As + (wm * 64 + t * 16 + l15) * 64 + ca);
#pragma unroll
      for (int t = 0; t < 4; ++t)
        bfr[t] = *(const bf16x8*)(Bs + (wn * 64 + t * 16 + l15) * 64 + ca);
#pragma unroll
      for (int mt = 0; mt < 4; ++mt)
#pragma unroll
        for (int nt = 0; nt < 4; ++nt)
          acc[mt][nt] = __builtin_amdgcn_mfma_f32_16x16x32_bf16(af[mt], bfr[nt],
                                                                acc[mt][nt], 0, 0, 0);
    }
  }

  __syncthreads();  // all K-loop LDS reads complete before aliasing
  u16* Cs = smem;   // [128][128] u16 = 32 KB
#pragma unroll
  for (int mt = 0; mt < 4; ++mt)
#pragma unroll
    for (int nt = 0; nt < 4; ++nt) {
      const int row = wm * 64 + mt * 16 + quad * 4;
      const int col = wn * 64 + nt * 16 + l15;
#pragma unroll
      for (int j = 0; j < 4; ++j)
        Cs[(row + j) * 128 + col] = f2b(acc[mt][nt][j]);
    }
  __syncthreads();
  const size_t ybase = (size_t)(bm * 128) * 12288 + (size_t)bn * 128;
#pragma unroll
  for (int q = 0; q < 8; ++q) {
    const int id = q * 256 + tid;           // 0..2047
    const int r = id >> 4, c = (id & 15) * 8;
    *(uint4*)(Y + ybase + (size_t)r * 12288 + c) = *(const uint4*)(Cs + r * 128 + c);
  }
}

// ---------------- kernel 3: epilogue v3 + self-detect ----------------------
__global__ __launch_bounds__(256) void epilogue_kernel(
    const u16* __restrict__ Y, const u16* __restrict__ Fx,
    const float* __restrict__ deg, const float* __restrict__ logd,
    const float* __restrict__ dsum, const u16* __restrict__ ThT,
    const void* __restrict__ Bias, void* __restrict__ out,
    const u16* __restrict__ Xu) {
  __shared__ __attribute__((aligned(16))) u16 Ys[32 * 264];
  __shared__ u16 Xs[32 * 33];
  __shared__ __attribute__((aligned(16))) u16 feats[32 * 680];
  __shared__ int sbad;
  const int tid = threadIdx.x;
  if (tid == 0) sbad = 0;
  __syncthreads();
  {
    int bad = 0;
#pragma unroll
    for (int q = 0; q < 8; ++q) {
      float a = fabsf(b2f(Xu[q * 256 + tid]));
      if (!(a <= 1e4f)) bad = 1;
    }
    if (bad) atomicOr(&sbad, 1);
  }
  __syncthreads();
  const int isf32 = sbad;

  const int nc = blockIdx.x;   // 0..63 node chunk
  const int b  = blockIdx.y;   // 0..3
  const int pz = blockIdx.z;   // 0..1
  const float delta = dsum[0] * (1.0f / 2048.0f);

  const int nl = tid >> 3;     // 0..31 local node
  const int chg = tid & 7;     // 4 channels each
  const int inode = nc * 32 + nl;
  const float d = fmaxf(deg[inode], EPSF);
  const float rd = 1.0f / d;
  const float s = logd[inode] / delta;
  const float is = 1.0f / fmaxf(s, EPSF);

  const int wave = tid >> 6, lane = tid & 63;
  const int l15 = lane & 15, quad = lane >> 4;
  const int mt = wave >> 1, nt = wave & 1;  // 2x2 of 16x16
  const int o = nt * 16 + l15;
  const float bias = isf32 ? ((const float*)Bias)[o] : b2f(((const u16*)Bias)[o]);

  float r[4][6];

#pragma unroll
  for (int pp = 0; pp < 6; ++pp) {
    const int p = pz * 6 + pp;
    const int bp = b * 12 + p;
    __syncthreads();  // prior iter's LDS reads complete
#pragma unroll
    for (int q = 0; q < 4; ++q) {
      const int id = q * 256 + tid;                 // 0..1023
      const int rr = id >> 5, ck = id & 31;
      *(uint4*)(Ys + rr * 264 + ck * 8) =
          *(const uint4*)(Y + (size_t)(nc * 32 + rr) * 12288 + (size_t)bp * 256 + ck * 8);
      Xs[rr * 33 + ck] = Fx[(size_t)(bp * 256 + rr) * 2048 + nc * 32 + ck];
    }
    __syncthreads();

    const u16* yr = Ys + nl * 264;
#pragma unroll
    for (int cc = 0; cc < 4; ++cc) {
      const int ch = chg * 4 + cc;
      const float m1 = b2f(yr[ch]) * rd;
      const float m2 = b2f(yr[32 + ch]) * rd;
      const float m3 = b2f(yr[64 + ch]) * rd;
      const float m4 = b2f(yr[96 + ch]) * rd;
      const float smx = b2f(yr[128 + ch]) / (b2f(yr[160 + ch]) + EPSF);
      const float smn = b2f(yr[192 + ch]) / (b2f(yr[224 + ch]) + EPSF);
      const float x = b2f(Xs[ch * 33 + nl]);
      const float var = fmaxf(m2 - m1 * m1, 0.f);
      const float stdv = sqrtf(var + EPSF);
      const float x2 = x * x, x3 = x2 * x, x4 = x2 * x2;
      const float dist = x2 - 2.f * x * m1 + m2;
      const float ed2 = x4 - 4.f * x3 * m1 + 6.f * x2 * m2 - 4.f * x * m3 + m4;
      const float dstd = sqrtf(fmaxf(ed2 - dist * dist, 0.f) + EPSF);
      const float f7[7] = {smn, smx, m1, stdv, var, dist, dstd};
#pragma unroll
      for (int a = 0; a < 7; ++a) {
        const int k = a * 32 + ch;
        feats[nl * 680 + k]       = f2b(f7[a]);
        feats[nl * 680 + 224 + k] = f2b(f7[a] * s);
        feats[nl * 680 + 448 + k] = f2b(f7[a] * is);
      }
    }
    __syncthreads();

    f32x4 acc = (f32x4){0.f, 0.f, 0.f, 0.f};
#pragma unroll
    for (int kt = 0; kt < 21; ++kt) {  // K = 672
      bf16x8 a  = *(const bf16x8*)(feats + (mt * 16 + l15) * 680 + kt * 32 + quad * 8);
      bf16x8 bb = *(const bf16x8*)(ThT + (size_t)o * 672 + kt * 32 + quad * 8);
      acc = __builtin_amdgcn_mfma_f32_16x16x32_bf16(a, bb, acc, 0, 0, 0);
    }
#pragma unroll
    for (int j = 0; j < 4; ++j) r[j][pp] = acc[j];
  }

#pragma unroll
  for (int j = 0; j < 4; ++j) {
    const int node = mt * 16 + quad * 4 + j;
    const int ig = nc * 32 + node;
    const size_t oi = ((size_t)(b * 32 + o) * 2048 + ig) * 12 + pz * 6;
    float v[6];
#pragma unroll
    for (int k = 0; k < 6; ++k) {
      float t = r[j][k] + bias;
      v[k] = t > 0.f ? t : 0.01f * t;   // leaky_relu
    }
    if (isf32) {
      float* dst = (float*)out + oi;   // 8B-aligned
      *(float2*)(dst)     = (float2){v[0], v[1]};
      *(float2*)(dst + 2) = (float2){v[2], v[3]};
      *(float2*)(dst + 4) = (float2){v[4], v[5]};
    } else {
      u16* dst = (u16*)out + oi;
#pragma unroll
      for (int k = 0; k < 6; ++k) dst[k] = f2b(v[k]);
    }
  }
}

// ---------------------------------------------------------------------------
extern "C" void kernel_launch(void* const* d_in, const int* in_sizes, int n_in,
                              void* d_out, int out_size, void* d_ws, size_t ws_size,
                              hipStream_t stream) {
  const void* X    = d_in[0];
  const void* A    = d_in[1];
  const void* Th   = d_in[2];
  const void* Bias = d_in[3];
  char* ws = (char*)d_ws;

  u16*   Ft   = (u16*)(ws);                       // 12288*2048*2 = 50331648
  u16*   Y    = (u16*)(ws + 50331648);            // 2048*12288*2 = 50331648
  u16*   Abf  = (u16*)(ws + 100663296);           // 2048*2048*2  = 8388608
  float* deg  = (float*)(ws + 109051904);         // 8192
  float* logd = (float*)(ws + 109060096);         // 8192
  u16*   ThT  = (u16*)(ws + 109068288);           // 43008
  float* dsum = (float*)(ws + 109111296);         // 4

  hipMemsetAsync(dsum, 0, 4, stream);
  prep_kernel<<<3156, 256, 0, stream>>>(X, A, Th, Abf, Ft, deg, logd, dsum, ThT);
  gemm_kernel<<<1536, 256, 0, stream>>>(Abf, Ft, Y);
  epilogue_kernel<<<dim3(64, 4, 2), 256, 0, stream>>>(Y, Ft, deg, logd, dsum, ThT,
                                                      Bias, d_out, (const u16*)X);
}

// Round 9
// 214.853 us; speedup vs baseline: 2.8570x; 1.2279x over previous
//
#include <hip/hip_runtime.h>
#include <hip/hip_bf16.h>
#include <cstdint>
#include <cstddef>

typedef unsigned short u16;
typedef __bf16 bf16x8 __attribute__((ext_vector_type(8)));
typedef float f32x4 __attribute__((ext_vector_type(4)));
typedef unsigned int u32x4 __attribute__((ext_vector_type(4)));  // clang vec: ok for nontemporal builtins

#define EPSF 1e-5f

__device__ __forceinline__ float b2f(u16 u) {
  unsigned int i = ((unsigned int)u) << 16;
  return __builtin_bit_cast(float, i);
}
__device__ __forceinline__ u16 f2b(float f) {
  unsigned int u = __builtin_bit_cast(unsigned int, f);
  u = u + 0x7fffu + ((u >> 16) & 1u);  // round-to-nearest-even
  return (u16)(u >> 16);
}

// async global->LDS, 16B/lane.
__device__ __forceinline__ void async_load16(const u16* g, u16* l) {
  __builtin_amdgcn_global_load_lds(
      (__attribute__((address_space(1))) void*)(g),
      (__attribute__((address_space(3))) void*)(l), 16, 0, 0);
}

// ---------------- kernel 1: fused prep (A-convert+deg | build_f | thetaT) --
__global__ __launch_bounds__(256) void prep_kernel(
    const void* __restrict__ X, const void* __restrict__ A,
    const void* __restrict__ Th, u16* __restrict__ Abf, u16* __restrict__ Ft,
    float* __restrict__ deg, float* __restrict__ logd, u16* __restrict__ ThT) {
  __shared__ int sbad;
  __shared__ float Xl[256 * 13];
  __shared__ float red[4];
  const int tid = threadIdx.x;
  if (tid == 0) sbad = 0;
  __syncthreads();
  {
    const u16* Xu = (const u16*)X;
    int bad = 0;
#pragma unroll
    for (int q = 0; q < 8; ++q) {
      float a = fabsf(b2f(Xu[q * 256 + tid]));
      if (!(a <= 1e4f)) bad = 1;  // huge or NaN
    }
    if (bad) atomicOr(&sbad, 1);
  }
  __syncthreads();
  const int isf32 = sbad;
  const int bid = blockIdx.x;

  if (bid < 2048) {
    // ---- role A: convert A row -> bf16 AND compute degree in one pass
    const int row = bid;
    float s = 0.f;
    uint4 st;
    if (isf32) {
      const float4* Af = (const float4*)A + (size_t)row * 512 + tid * 2;
      float4 a = Af[0], b = Af[1];
      s = a.x + a.y + a.z + a.w + b.x + b.y + b.z + b.w;
      u16 o[8] = {f2b(a.x), f2b(a.y), f2b(a.z), f2b(a.w),
                  f2b(b.x), f2b(b.y), f2b(b.z), f2b(b.w)};
      st = *(const uint4*)o;
    } else {
      st = ((const uint4*)A)[(size_t)row * 256 + tid];
      const u16* o = (const u16*)&st;
#pragma unroll
      for (int k = 0; k < 8; ++k) s += b2f(o[k]);
    }
    *(uint4*)(Abf + (size_t)row * 2048 + tid * 8) = st;
#pragma unroll
    for (int off = 32; off > 0; off >>= 1) s += __shfl_down(s, off, 64);
    const int lane = tid & 63, w = tid >> 6;
    if (lane == 0) red[w] = s;
    __syncthreads();
    if (tid == 0) {
      float t = red[0] + red[1] + red[2] + red[3];
      deg[row] = t;
      logd[row] = logf(t + 1.f);
    }
  } else if (bid < 3072) {
    // ---- role B: build F^T [12288][2048] bf16
    const int blk = bid - 2048;      // b*256 + ch*8 + mc
    const int mc = blk & 7;
    const int ch = (blk >> 3) & 31;
    const int b  = blk >> 8;
    const size_t g0 = ((size_t)(b * 32 + ch) * 2048 + (size_t)mc * 256) * 12;
    if (isf32) {
      const float4* Xg = (const float4*)((const float*)X + g0);
#pragma unroll
      for (int q = 0; q < 3; ++q) {
        const int id = q * 256 + tid;        // 0..767 float4s
        const float4 v = Xg[id];
        const int j = id * 4, row = j / 12, col = j % 12;  // col in {0,4,8}
        Xl[row * 13 + col]     = v.x;
        Xl[row * 13 + col + 1] = v.y;
        Xl[row * 13 + col + 2] = v.z;
        Xl[row * 13 + col + 3] = v.w;
      }
    } else {
      const u16* Xg = (const u16*)X + g0;
#pragma unroll
      for (int q = 0; q < 12; ++q) {
        const int id = q * 256 + tid;        // 0..3071 u16s
        Xl[(id / 12) * 13 + id % 12] = b2f(Xg[id]);
      }
    }
    __syncthreads();
    const int m = tid;
    const int gm = mc * 256 + m;
#pragma unroll
    for (int p = 0; p < 12; ++p) {
      const float x = Xl[m * 13 + p];
      const float x2 = x * x, x3 = x2 * x, x4 = x2 * x2;
      const float e = __expf(x), en = __expf(-x);
      const float vals[8] = {x, x2, x3, x4, x * e, e, x * en, en};
      const size_t cb = (size_t)(b * 12 + p) * 256 + ch;
#pragma unroll
      for (int f = 0; f < 8; ++f)
        Ft[(cb + (size_t)f * 32) * 2048 + gm] = f2b(vals[f]);
    }
  } else {
    // ---- role C: Theta transpose -> ThT [32][672]
    const int e = (bid - 3072) * 256 + tid;
    if (e < 21504) {
      const int k = e >> 5, o = e & 31;
      ThT[o * 672 + k] = isf32 ? f2b(((const float*)Th)[e]) : ((const u16*)Th)[e];
    }
  }
}

// ---------------- kernel 2: GEMM Y = Abf @ F --------------------------------
// r8: XCD partition = 4 bm x 48 bn rectangle per XCD, bm-fastest order:
// A working set 2MB L2-resident; each Ft tile consumed by 4 consecutive
// blocks (MSHR-merged) -> per-XCD L2-miss ~26MB, total ~208MB (was 397MB,
// = 8 XCDs x full-Ft re-read under the r3 2-bm partition). Y stores
// non-temporal so the 49MB stream doesn't evict A from L2.
__global__ __launch_bounds__(256) void gemm_kernel(const u16* __restrict__ A,
                                                   const u16* __restrict__ Ft,
                                                   u16* __restrict__ Y) {
  __shared__ __attribute__((aligned(16))) u16 smem[2 * 128 * 64];  // 32 KB
  u16* As = smem;             // [128][64]
  u16* Bs = smem + 128 * 64;  // [128][64]
  const int tid = threadIdx.x;
  const int wave = tid >> 6;
  const int lane = tid & 63;
  const int l15 = lane & 15;
  const int quad = lane >> 4;
  const int wm = wave >> 1;
  const int wn = wave & 1;

  const int i4 = blockIdx.x;         // 0..1535
  const int xcd = i4 & 7;
  const int s4 = i4 >> 3;            // 0..191
  const int bm = (xcd >> 1) * 4 + (s4 & 3);
  const int bn = (xcd & 1) * 48 + (s4 >> 2);

  const int lrow = lane >> 3;                    // 0..7
  const int schunk = (lane & 7) ^ lrow;          // swizzled source chunk
  const u16* gA = A  + (size_t)(bm * 128 + wave * 32 + lrow) * 2048 + schunk * 8;
  const u16* gB = Ft + (size_t)(bn * 128 + wave * 32 + lrow) * 2048 + schunk * 8;
  u16* lA = As + wave * 32 * 64 + lane * 8;  // per-lane dest (base + lane*16B)
  u16* lB = Bs + wave * 32 * 64 + lane * 8;

  f32x4 acc[4][4];
#pragma unroll
  for (int i = 0; i < 4; ++i)
#pragma unroll
    for (int j = 0; j < 4; ++j) acc[i][j] = (f32x4){0.f, 0.f, 0.f, 0.f};

  for (int kk = 0; kk < 2048; kk += 64) {
    __syncthreads();  // prev iter's LDS reads done before overwrite
#pragma unroll
    for (int i = 0; i < 4; ++i) {
      async_load16(gA + (size_t)i * (8 * 2048) + kk, lA + i * (8 * 64));
      async_load16(gB + (size_t)i * (8 * 2048) + kk, lB + i * (8 * 64));
    }
    __syncthreads();  // compiler drains vmcnt(0) before s_barrier
#pragma unroll
    for (int ks = 0; ks < 2; ++ks) {
      const int ca = ((ks * 4 + quad) ^ (l15 & 7)) * 8;  // un-swizzle chunk
      bf16x8 af[4], bfr[4];
#pragma unroll
      for (int t = 0; t < 4; ++t)
        af[t] = *(const bf16x8*)(As + (wm * 64 + t * 16 + l15) * 64 + ca);
#pragma unroll
      for (int t = 0; t < 4; ++t)
        bfr[t] = *(const bf16x8*)(Bs + (wn * 64 + t * 16 + l15) * 64 + ca);
#pragma unroll
      for (int mt = 0; mt < 4; ++mt)
#pragma unroll
        for (int nt = 0; nt < 4; ++nt)
          acc[mt][nt] = __builtin_amdgcn_mfma_f32_16x16x32_bf16(af[mt], bfr[nt],
                                                                acc[mt][nt], 0, 0, 0);
    }
  }

  __syncthreads();  // all K-loop LDS reads complete before aliasing
  u16* Cs = smem;   // [128][128] u16 = 32 KB
#pragma unroll
  for (int mt = 0; mt < 4; ++mt)
#pragma unroll
    for (int nt = 0; nt < 4; ++nt) {
      const int row = wm * 64 + mt * 16 + quad * 4;
      const int col = wn * 64 + nt * 16 + l15;
#pragma unroll
      for (int j = 0; j < 4; ++j)
        Cs[(row + j) * 128 + col] = f2b(acc[mt][nt][j]);
    }
  __syncthreads();
  const size_t ybase = (size_t)(bm * 128) * 12288 + (size_t)bn * 128;
#pragma unroll
  for (int q = 0; q < 8; ++q) {
    const int id = q * 256 + tid;           // 0..2047
    const int r = id >> 4, c = (id & 15) * 8;
    __builtin_nontemporal_store(*(const u32x4*)(Cs + r * 128 + c),
                                (u32x4*)(Y + ybase + (size_t)r * 12288 + c));
  }
}

// ---------------- kernel 3: epilogue v3 + self-detect + self-delta ---------
__global__ __launch_bounds__(256) void epilogue_kernel(
    const u16* __restrict__ Y, const u16* __restrict__ Fx,
    const float* __restrict__ deg, const float* __restrict__ logd,
    const u16* __restrict__ ThT, const void* __restrict__ Bias,
    void* __restrict__ out, const u16* __restrict__ Xu) {
  __shared__ __attribute__((aligned(16))) u16 Ys[32 * 264];
  __shared__ u16 Xs[32 * 33];
  __shared__ __attribute__((aligned(16))) u16 feats[32 * 680];
  __shared__ int sbad;
  __shared__ float red[4];
  const int tid = threadIdx.x;
  if (tid == 0) sbad = 0;
  __syncthreads();
  float ls = 0.f;
  {
    int bad = 0;
#pragma unroll
    for (int q = 0; q < 8; ++q) {
      float a = fabsf(b2f(Xu[q * 256 + tid]));
      if (!(a <= 1e4f)) bad = 1;
      ls += logd[q * 256 + tid];
    }
    if (bad) atomicOr(&sbad, 1);
  }
#pragma unroll
  for (int off = 32; off > 0; off >>= 1) ls += __shfl_down(ls, off, 64);
  if ((tid & 63) == 0) red[tid >> 6] = ls;
  __syncthreads();
  const int isf32 = sbad;
  const float delta = (red[0] + red[1] + red[2] + red[3]) * (1.0f / 2048.0f);

  const int nc = blockIdx.x;   // 0..63 node chunk
  const int b  = blockIdx.y;   // 0..3
  const int pz = blockIdx.z;   // 0..1

  const int nl = tid >> 3;     // 0..31 local node
  const int chg = tid & 7;     // 4 channels each
  const int inode = nc * 32 + nl;
  const float d = fmaxf(deg[inode], EPSF);
  const float rd = 1.0f / d;
  const float s = logd[inode] / delta;
  const float is = 1.0f / fmaxf(s, EPSF);

  const int wave = tid >> 6, lane = tid & 63;
  const int l15 = lane & 15, quad = lane >> 4;
  const int mt = wave >> 1, nt = wave & 1;  // 2x2 of 16x16
  const int o = nt * 16 + l15;
  const float bias = isf32 ? ((const float*)Bias)[o] : b2f(((const u16*)Bias)[o]);

  float r[4][6];

#pragma unroll
  for (int pp = 0; pp < 6; ++pp) {
    const int p = pz * 6 + pp;
    const int bp = b * 12 + p;
    __syncthreads();  // prior iter's LDS reads complete
#pragma unroll
    for (int q = 0; q < 4; ++q) {
      const int id = q * 256 + tid;                 // 0..1023
      const int rr = id >> 5, ck = id & 31;
      *(u32x4*)(Ys + rr * 264 + ck * 8) = __builtin_nontemporal_load(
          (const u32x4*)(Y + (size_t)(nc * 32 + rr) * 12288 + (size_t)bp * 256 + ck * 8));
      Xs[rr * 33 + ck] = Fx[(size_t)(bp * 256 + rr) * 2048 + nc * 32 + ck];
    }
    __syncthreads();

    const u16* yr = Ys + nl * 264;
#pragma unroll
    for (int cc = 0; cc < 4; ++cc) {
      const int ch = chg * 4 + cc;
      const float m1 = b2f(yr[ch]) * rd;
      const float m2 = b2f(yr[32 + ch]) * rd;
      const float m3 = b2f(yr[64 + ch]) * rd;
      const float m4 = b2f(yr[96 + ch]) * rd;
      const float smx = b2f(yr[128 + ch]) / (b2f(yr[160 + ch]) + EPSF);
      const float smn = b2f(yr[192 + ch]) / (b2f(yr[224 + ch]) + EPSF);
      const float x = b2f(Xs[ch * 33 + nl]);
      const float var = fmaxf(m2 - m1 * m1, 0.f);
      const float stdv = sqrtf(var + EPSF);
      const float x2 = x * x, x3 = x2 * x, x4 = x2 * x2;
      const float dist = x2 - 2.f * x * m1 + m2;
      const float ed2 = x4 - 4.f * x3 * m1 + 6.f * x2 * m2 - 4.f * x * m3 + m4;
      const float dstd = sqrtf(fmaxf(ed2 - dist * dist, 0.f) + EPSF);
      const float f7[7] = {smn, smx, m1, stdv, var, dist, dstd};
#pragma unroll
      for (int a = 0; a < 7; ++a) {
        const int k = a * 32 + ch;
        feats[nl * 680 + k]       = f2b(f7[a]);
        feats[nl * 680 + 224 + k] = f2b(f7[a] * s);
        feats[nl * 680 + 448 + k] = f2b(f7[a] * is);
      }
    }
    __syncthreads();

    f32x4 acc = (f32x4){0.f, 0.f, 0.f, 0.f};
#pragma unroll
    for (int kt = 0; kt < 21; ++kt) {  // K = 672
      bf16x8 a  = *(const bf16x8*)(feats + (mt * 16 + l15) * 680 + kt * 32 + quad * 8);
      bf16x8 bb = *(const bf16x8*)(ThT + (size_t)o * 672 + kt * 32 + quad * 8);
      acc = __builtin_amdgcn_mfma_f32_16x16x32_bf16(a, bb, acc, 0, 0, 0);
    }
#pragma unroll
    for (int j = 0; j < 4; ++j) r[j][pp] = acc[j];
  }

#pragma unroll
  for (int j = 0; j < 4; ++j) {
    const int node = mt * 16 + quad * 4 + j;
    const int ig = nc * 32 + node;
    const size_t oi = ((size_t)(b * 32 + o) * 2048 + ig) * 12 + pz * 6;
    float v[6];
#pragma unroll
    for (int k = 0; k < 6; ++k) {
      float t = r[j][k] + bias;
      v[k] = t > 0.f ? t : 0.01f * t;   // leaky_relu
    }
    if (isf32) {
      float* dst = (float*)out + oi;   // 8B-aligned
      *(float2*)(dst)     = (float2){v[0], v[1]};
      *(float2*)(dst + 2) = (float2){v[2], v[3]};
      *(float2*)(dst + 4) = (float2){v[4], v[5]};
    } else {
      u16* dst = (u16*)out + oi;
#pragma unroll
      for (int k = 0; k < 6; ++k) dst[k] = f2b(v[k]);
    }
  }
}

// ---------------------------------------------------------------------------
extern "C" void kernel_launch(void* const* d_in, const int* in_sizes, int n_in,
                              void* d_out, int out_size, void* d_ws, size_t ws_size,
                              hipStream_t stream) {
  const void* X    = d_in[0];
  const void* A    = d_in[1];
  const void* Th   = d_in[2];
  const void* Bias = d_in[3];
  char* ws = (char*)d_ws;

  u16*   Ft   = (u16*)(ws);                       // 12288*2048*2 = 50331648
  u16*   Y    = (u16*)(ws + 50331648);            // 2048*12288*2 = 50331648
  u16*   Abf  = (u16*)(ws + 100663296);           // 2048*2048*2  = 8388608
  float* deg  = (float*)(ws + 109051904);         // 8192
  float* logd = (float*)(ws + 109060096);         // 8192
  u16*   ThT  = (u16*)(ws + 109068288);           // 43008

  prep_kernel<<<3156, 256, 0, stream>>>(X, A, Th, Abf, Ft, deg, logd, ThT);
  gemm_kernel<<<1536, 256, 0, stream>>>(Abf, Ft, Y);
  epilogue_kernel<<<dim3(64, 4, 2), 256, 0, stream>>>(Y, Ft, deg, logd, ThT,
                                                      Bias, d_out, (const u16*)X);
}